// Round 1
// baseline (1163.775 us; speedup 1.0000x reference)
//
#include <hip/hip_runtime.h>

#define NN     50000
#define E_RAW  800000
#define ETOT   (E_RAW + NN)   /* 850000: edges + self loops */
#define FIN    128
#define FH     256            /* HEADS*HID */
#define NEG    0.2f

static __device__ __forceinline__ float leaky(float v) { return v > 0.f ? v : NEG * v; }

// ---------------------------------------------------------------------------
// K1: h1 = x @ W1 + b1.  64 nodes x 256 cols per 256-thread block, 8x8 reg tile.
// LDS: Ws[32][256] (32KB) + Xs[32][64] (8KB) = 40KB -> 4 blocks/CU.
// lane&7 -> node-subtile, lane>>3 -> col-subtile: both LDS compute reads are
// 8 distinct addresses spread 2-per-bank-group => 2-way (free).
// ---------------------------------------------------------------------------
__global__ __launch_bounds__(256) void k_gemm1(const float* __restrict__ x,
                                               const float* __restrict__ W1,
                                               const float* __restrict__ b1,
                                               float* __restrict__ h1)
{
    __shared__ float Ws[32][256];
    __shared__ float Xs[32][64];
    const int t = threadIdx.x;
    const int tnode = t & 7;    // 0..7  -> nodes tnode*8 .. +8
    const int tcol  = t >> 3;   // 0..31 -> cols  tcol*8 .. +8
    const int n0 = blockIdx.x * 64;

    float acc[8][8];
#pragma unroll
    for (int i = 0; i < 8; i++)
#pragma unroll
        for (int j = 0; j < 8; j++) acc[i][j] = 0.f;

    const int xn = t >> 2;   // 0..63 node for X staging
    const int xc = t & 3;    // 0..3  k-chunk for X staging

    for (int kk = 0; kk < FIN; kk += 32) {
        // stage W1[kk..kk+32][0..256): 2048 float4, coalesced
#pragma unroll
        for (int i = 0; i < 8; i++) {
            int f4 = t + i * 256;
            int r  = f4 >> 6;
            int c4 = f4 & 63;
            float4 v = *(const float4*)&W1[(kk + r) * FH + c4 * 4];
            *(float4*)&Ws[r][c4 * 4] = v;
        }
        // stage x[n0..n0+64][kk..kk+32) transposed into Xs[k][n]
        {
            int nn = n0 + xn; if (nn >= NN) nn = NN - 1;
            const float* xp = &x[nn * FIN + kk + xc * 8];
            float4 va = *(const float4*)&xp[0];
            float4 vb = *(const float4*)&xp[4];
            Xs[xc * 8 + 0][xn] = va.x; Xs[xc * 8 + 1][xn] = va.y;
            Xs[xc * 8 + 2][xn] = va.z; Xs[xc * 8 + 3][xn] = va.w;
            Xs[xc * 8 + 4][xn] = vb.x; Xs[xc * 8 + 5][xn] = vb.y;
            Xs[xc * 8 + 6][xn] = vb.z; Xs[xc * 8 + 7][xn] = vb.w;
        }
        __syncthreads();
#pragma unroll
        for (int k = 0; k < 32; k++) {
            float4 wa = *(const float4*)&Ws[k][tcol * 8];
            float4 wb = *(const float4*)&Ws[k][tcol * 8 + 4];
            float4 xa = *(const float4*)&Xs[k][tnode * 8];
            float4 xb = *(const float4*)&Xs[k][tnode * 8 + 4];
            float w[8]  = {wa.x, wa.y, wa.z, wa.w, wb.x, wb.y, wb.z, wb.w};
            float xv[8] = {xa.x, xa.y, xa.z, xa.w, xb.x, xb.y, xb.z, xb.w};
#pragma unroll
            for (int i = 0; i < 8; i++)
#pragma unroll
                for (int j = 0; j < 8; j++) acc[i][j] += xv[i] * w[j];
        }
        __syncthreads();
    }

    float bb[8];
#pragma unroll
    for (int j = 0; j < 8; j++) bb[j] = b1[tcol * 8 + j];
#pragma unroll
    for (int i = 0; i < 8; i++) {
        int n = n0 + tnode * 8 + i;
        if (n < NN) {
            float4 o0, o1;
            o0.x = acc[i][0] + bb[0]; o0.y = acc[i][1] + bb[1];
            o0.z = acc[i][2] + bb[2]; o0.w = acc[i][3] + bb[3];
            o1.x = acc[i][4] + bb[4]; o1.y = acc[i][5] + bb[5];
            o1.z = acc[i][6] + bb[6]; o1.w = acc[i][7] + bb[7];
            *(float4*)&h1[n * FH + tcol * 8]     = o0;
            *(float4*)&h1[n * FH + tcol * 8 + 4] = o1;
        }
    }
}

// ---------------------------------------------------------------------------
// K2: per-node attention logits a_s1/a_d1 [N,4].  One wave per node.
// ---------------------------------------------------------------------------
__global__ __launch_bounds__(256) void k_att1(const float* __restrict__ h1,
                                              const float* __restrict__ att_src,
                                              const float* __restrict__ att_dst,
                                              float* __restrict__ a_s,
                                              float* __restrict__ a_d)
{
    const int lane = threadIdx.x & 63;
    const int n = blockIdx.x * 4 + (threadIdx.x >> 6);
    if (n >= NN) return;
    float s[4], d[4];
#pragma unroll
    for (int h = 0; h < 4; h++) {
        float v = h1[n * FH + h * 64 + lane];
        s[h] = v * att_src[h * 64 + lane];
        d[h] = v * att_dst[h * 64 + lane];
    }
#pragma unroll
    for (int off = 32; off; off >>= 1) {
#pragma unroll
        for (int h = 0; h < 4; h++) {
            s[h] += __shfl_xor(s[h], off);
            d[h] += __shfl_xor(d[h], off);
        }
    }
    if (lane == 0) {
#pragma unroll
        for (int h = 0; h < 4; h++) { a_s[n * 4 + h] = s[h]; a_d[n * 4 + h] = d[h]; }
    }
}

// ---------------------------------------------------------------------------
// K3: layer-1 edge pass A: ex = exp(leaky(a_s[src]+a_d[dst])); z[dst] += ex
// (softmax without max-subtraction: mathematically identical, |e| <~ 8)
// ---------------------------------------------------------------------------
__global__ __launch_bounds__(256) void k_edge1_a(const int* __restrict__ ei,
                                                 const float* __restrict__ a_s,
                                                 const float* __restrict__ a_d,
                                                 float* __restrict__ ex1,
                                                 float* __restrict__ z1)
{
    const int e = blockIdx.x * 256 + threadIdx.x;
    if (e >= ETOT) return;
    int s, d;
    if (e < E_RAW) { s = ei[e]; d = ei[E_RAW + e]; } else { s = e - E_RAW; d = s; }
    float4 as = *(const float4*)&a_s[s * 4];
    float4 ad = *(const float4*)&a_d[d * 4];
    float4 ex;
    ex.x = __expf(leaky(as.x + ad.x));
    ex.y = __expf(leaky(as.y + ad.y));
    ex.z = __expf(leaky(as.z + ad.z));
    ex.w = __expf(leaky(as.w + ad.w));
    *(float4*)&ex1[e * 4] = ex;
    atomicAdd(&z1[d * 4 + 0], ex.x);
    atomicAdd(&z1[d * 4 + 1], ex.y);
    atomicAdd(&z1[d * 4 + 2], ex.z);
    atomicAdd(&z1[d * 4 + 3], ex.w);
}

// ---------------------------------------------------------------------------
// K4: layer-1 aggregation (expected bottleneck).  One wave per edge:
// lane l handles channel l of each head; out1[dst] += h1[src]*alpha.
// ---------------------------------------------------------------------------
__global__ __launch_bounds__(256) void k_edge1_b(const int* __restrict__ ei,
                                                 const float* __restrict__ ex1,
                                                 const float* __restrict__ z1,
                                                 const float* __restrict__ h1,
                                                 float* __restrict__ out1)
{
    const int e = blockIdx.x * 4 + (threadIdx.x >> 6);
    const int lane = threadIdx.x & 63;
    if (e >= ETOT) return;
    int s, d;
    if (e < E_RAW) { s = ei[e]; d = ei[E_RAW + e]; } else { s = e - E_RAW; d = s; }
    float4 ex = *(const float4*)&ex1[e * 4];
    float4 z  = *(const float4*)&z1[d * 4];
    float al[4] = {ex.x / z.x, ex.y / z.y, ex.z / z.z, ex.w / z.w};
#pragma unroll
    for (int h = 0; h < 4; h++) {
        float v = h1[s * FH + h * 64 + lane] * al[h];
        atomicAdd(&out1[d * FH + h * 64 + lane], v);
    }
}

// ---------------------------------------------------------------------------
// K5: layer-2 linear (+fused b1-add and ELU) + attention logits.
// One wave per node; h2[n,2], a_s2[n], a_d2[n].
// ---------------------------------------------------------------------------
__global__ __launch_bounds__(256) void k_lin2(const float* __restrict__ out1,
                                              const float* __restrict__ b1,
                                              const float* __restrict__ W2,
                                              const float* __restrict__ att_src2,
                                              const float* __restrict__ att_dst2,
                                              float* __restrict__ h2,
                                              float* __restrict__ a_s2,
                                              float* __restrict__ a_d2)
{
    const int lane = threadIdx.x & 63;
    const int n = blockIdx.x * 4 + (threadIdx.x >> 6);
    if (n >= NN) return;
    float acc0 = 0.f, acc1 = 0.f;
#pragma unroll
    for (int m = 0; m < 4; m++) {
        int j = m * 64 + lane;
        float v = out1[n * FH + j] + b1[j];
        v = v > 0.f ? v : expm1f(v);   // ELU
        acc0 += v * W2[j * 2 + 0];
        acc1 += v * W2[j * 2 + 1];
    }
#pragma unroll
    for (int off = 32; off; off >>= 1) {
        acc0 += __shfl_xor(acc0, off);
        acc1 += __shfl_xor(acc1, off);
    }
    if (lane == 0) {
        h2[n * 2 + 0] = acc0;
        h2[n * 2 + 1] = acc1;
        a_s2[n] = acc0 * att_src2[0] + acc1 * att_src2[1];
        a_d2[n] = acc0 * att_dst2[0] + acc1 * att_dst2[1];
    }
}

// ---------------------------------------------------------------------------
// K6: layer-2 edge pass A (1 head)
// ---------------------------------------------------------------------------
__global__ __launch_bounds__(256) void k_edge2_a(const int* __restrict__ ei,
                                                 const float* __restrict__ a_s,
                                                 const float* __restrict__ a_d,
                                                 float* __restrict__ ex2,
                                                 float* __restrict__ z2)
{
    const int e = blockIdx.x * 256 + threadIdx.x;
    if (e >= ETOT) return;
    int s, d;
    if (e < E_RAW) { s = ei[e]; d = ei[E_RAW + e]; } else { s = e - E_RAW; d = s; }
    float v = __expf(leaky(a_s[s] + a_d[d]));
    ex2[e] = v;
    atomicAdd(&z2[d], v);
}

// ---------------------------------------------------------------------------
// K7: layer-2 aggregation: out2[dst, 0..2) += h2[src]*alpha
// ---------------------------------------------------------------------------
__global__ __launch_bounds__(256) void k_edge2_b(const int* __restrict__ ei,
                                                 const float* __restrict__ ex2,
                                                 const float* __restrict__ z2,
                                                 const float* __restrict__ h2,
                                                 float* __restrict__ out2)
{
    const int e = blockIdx.x * 256 + threadIdx.x;
    if (e >= ETOT) return;
    int s, d;
    if (e < E_RAW) { s = ei[e]; d = ei[E_RAW + e]; } else { s = e - E_RAW; d = s; }
    float al = ex2[e] / z2[d];
    atomicAdd(&out2[d * 2 + 0], h2[s * 2 + 0] * al);
    atomicAdd(&out2[d * 2 + 1], h2[s * 2 + 1] * al);
}

// ---------------------------------------------------------------------------
// K8: final: out = out2 + b2
// ---------------------------------------------------------------------------
__global__ __launch_bounds__(256) void k_final(const float* __restrict__ out2,
                                               const float* __restrict__ b2,
                                               float* __restrict__ out)
{
    const int i = blockIdx.x * 256 + threadIdx.x;
    if (i < NN * 2) out[i] = out2[i] + b2[i & 1];
}

extern "C" void kernel_launch(void* const* d_in, const int* in_sizes, int n_in,
                              void* d_out, int out_size, void* d_ws, size_t ws_size,
                              hipStream_t stream)
{
    const float* x        = (const float*)d_in[0];
    const int*   ei       = (const int*)d_in[1];
    const float* W1       = (const float*)d_in[2];
    const float* att_src1 = (const float*)d_in[3];
    const float* att_dst1 = (const float*)d_in[4];
    const float* b1       = (const float*)d_in[5];
    const float* W2       = (const float*)d_in[6];
    const float* att_src2 = (const float*)d_in[7];
    const float* att_dst2 = (const float*)d_in[8];
    const float* b2       = (const float*)d_in[9];
    float* out = (float*)d_out;

    // --- workspace layout (floats) ---
    float* ws   = (float*)d_ws;
    float* h1   = ws;                          // 12,800,000
    float* zero0 = h1 + (size_t)NN * FH;
    float* out1 = zero0;                       // 12,800,000
    float* z1   = out1 + (size_t)NN * FH;      // 200,000
    float* z2   = z1 + NN * 4;                 // 50,000
    float* out2 = z2 + NN;                     // 100,000
    const size_t zero_count = (size_t)NN * FH + NN * 4 + NN + NN * 2;
    float* a_s1 = out2 + NN * 2;               // 200,000
    float* a_d1 = a_s1 + NN * 4;               // 200,000
    float* ex1  = a_d1 + NN * 4;               // 3,400,000
    float* h2   = ex1 + (size_t)ETOT * 4;      // 100,000
    float* a_s2 = h2 + NN * 2;                 // 50,000
    float* a_d2 = a_s2 + NN;                   // 50,000
    float* ex2  = a_d2 + NN;                   // 850,000

    hipMemsetAsync(zero0, 0, zero_count * sizeof(float), stream);

    k_gemm1<<<(NN + 63) / 64, 256, 0, stream>>>(x, W1, b1, h1);
    k_att1<<<(NN + 3) / 4, 256, 0, stream>>>(h1, att_src1, att_dst1, a_s1, a_d1);
    k_edge1_a<<<(ETOT + 255) / 256, 256, 0, stream>>>(ei, a_s1, a_d1, ex1, z1);
    k_edge1_b<<<(ETOT + 3) / 4, 256, 0, stream>>>(ei, ex1, z1, h1, out1);
    k_lin2<<<(NN + 3) / 4, 256, 0, stream>>>(out1, b1, W2, att_src2, att_dst2, h2, a_s2, a_d2);
    k_edge2_a<<<(ETOT + 255) / 256, 256, 0, stream>>>(ei, a_s2, a_d2, ex2, z2);
    k_edge2_b<<<(ETOT + 255) / 256, 256, 0, stream>>>(ei, ex2, z2, h2, out2);
    k_final<<<(NN * 2 + 255) / 256, 256, 0, stream>>>(out2, b2, out);
}

// Round 3
// 510.087 us; speedup vs baseline: 2.2815x; 2.2815x over previous
//
#include <hip/hip_runtime.h>

#define NN     50000
#define E_RAW  800000
#define ETOT   (E_RAW + NN)   /* 850000: edges + self loops */
#define FIN    128
#define FH     256            /* HEADS*HID */
#define NEG    0.2f

static __device__ __forceinline__ float leaky(float v) { return v > 0.f ? v : NEG * v; }

// ---------------------------------------------------------------------------
// K1: h1 = x @ W1 + b1.  64 nodes x 256 cols per 256-thread block, 8x8 reg tile.
// ---------------------------------------------------------------------------
__global__ __launch_bounds__(256) void k_gemm1(const float* __restrict__ x,
                                               const float* __restrict__ W1,
                                               const float* __restrict__ b1,
                                               float* __restrict__ h1)
{
    __shared__ float Ws[32][256];
    __shared__ float Xs[32][64];
    const int t = threadIdx.x;
    const int tnode = t & 7;
    const int tcol  = t >> 3;
    const int n0 = blockIdx.x * 64;

    float acc[8][8];
#pragma unroll
    for (int i = 0; i < 8; i++)
#pragma unroll
        for (int j = 0; j < 8; j++) acc[i][j] = 0.f;

    const int xn = t >> 2;
    const int xc = t & 3;

    for (int kk = 0; kk < FIN; kk += 32) {
#pragma unroll
        for (int i = 0; i < 8; i++) {
            int f4 = t + i * 256;
            int r  = f4 >> 6;
            int c4 = f4 & 63;
            float4 v = *(const float4*)&W1[(kk + r) * FH + c4 * 4];
            *(float4*)&Ws[r][c4 * 4] = v;
        }
        {
            int nn = n0 + xn; if (nn >= NN) nn = NN - 1;
            const float* xp = &x[nn * FIN + kk + xc * 8];
            float4 va = *(const float4*)&xp[0];
            float4 vb = *(const float4*)&xp[4];
            Xs[xc * 8 + 0][xn] = va.x; Xs[xc * 8 + 1][xn] = va.y;
            Xs[xc * 8 + 2][xn] = va.z; Xs[xc * 8 + 3][xn] = va.w;
            Xs[xc * 8 + 4][xn] = vb.x; Xs[xc * 8 + 5][xn] = vb.y;
            Xs[xc * 8 + 6][xn] = vb.z; Xs[xc * 8 + 7][xn] = vb.w;
        }
        __syncthreads();
#pragma unroll
        for (int k = 0; k < 32; k++) {
            float4 wa = *(const float4*)&Ws[k][tcol * 8];
            float4 wb = *(const float4*)&Ws[k][tcol * 8 + 4];
            float4 xa = *(const float4*)&Xs[k][tnode * 8];
            float4 xb = *(const float4*)&Xs[k][tnode * 8 + 4];
            float w[8]  = {wa.x, wa.y, wa.z, wa.w, wb.x, wb.y, wb.z, wb.w};
            float xv[8] = {xa.x, xa.y, xa.z, xa.w, xb.x, xb.y, xb.z, xb.w};
#pragma unroll
            for (int i = 0; i < 8; i++)
#pragma unroll
                for (int j = 0; j < 8; j++) acc[i][j] += xv[i] * w[j];
        }
        __syncthreads();
    }

    float bb[8];
#pragma unroll
    for (int j = 0; j < 8; j++) bb[j] = b1[tcol * 8 + j];
#pragma unroll
    for (int i = 0; i < 8; i++) {
        int n = n0 + tnode * 8 + i;
        if (n < NN) {
            float4 o0, o1;
            o0.x = acc[i][0] + bb[0]; o0.y = acc[i][1] + bb[1];
            o0.z = acc[i][2] + bb[2]; o0.w = acc[i][3] + bb[3];
            o1.x = acc[i][4] + bb[4]; o1.y = acc[i][5] + bb[5];
            o1.z = acc[i][6] + bb[6]; o1.w = acc[i][7] + bb[7];
            *(float4*)&h1[n * FH + tcol * 8]     = o0;
            *(float4*)&h1[n * FH + tcol * 8 + 4] = o1;
        }
    }
}

// ---------------------------------------------------------------------------
// K2: per-node attention logits a_s1/a_d1 [N,4].  One wave per node.
// ---------------------------------------------------------------------------
__global__ __launch_bounds__(256) void k_att1(const float* __restrict__ h1,
                                              const float* __restrict__ att_src,
                                              const float* __restrict__ att_dst,
                                              float* __restrict__ a_s,
                                              float* __restrict__ a_d)
{
    const int lane = threadIdx.x & 63;
    const int n = blockIdx.x * 4 + (threadIdx.x >> 6);
    if (n >= NN) return;
    float s[4], d[4];
#pragma unroll
    for (int h = 0; h < 4; h++) {
        float v = h1[n * FH + h * 64 + lane];
        s[h] = v * att_src[h * 64 + lane];
        d[h] = v * att_dst[h * 64 + lane];
    }
#pragma unroll
    for (int off = 32; off; off >>= 1) {
#pragma unroll
        for (int h = 0; h < 4; h++) {
            s[h] += __shfl_xor(s[h], off);
            d[h] += __shfl_xor(d[h], off);
        }
    }
    if (lane == 0) {
#pragma unroll
        for (int h = 0; h < 4; h++) { a_s[n * 4 + h] = s[h]; a_d[n * 4 + h] = d[h]; }
    }
}

// ---------------------------------------------------------------------------
// K3: per-dst degree histogram (one atomic per edge on 50k counters)
// ---------------------------------------------------------------------------
__global__ __launch_bounds__(256) void k_count(const int* __restrict__ ei,
                                               int* __restrict__ cnt)
{
    const int e = blockIdx.x * 256 + threadIdx.x;
    if (e >= ETOT) return;
    int d = (e < E_RAW) ? ei[E_RAW + e] : e - E_RAW;
    atomicAdd(&cnt[d], 1);
}

// ---------------------------------------------------------------------------
// K4: single-block exclusive scan over cnt[0..NN) -> ptr[0..NN], cursor copy.
// 1024 threads x 49 elements; LDS Hillis-Steele over 1024 partials.
// Second pass re-reads cnt (no per-thread array -> low VGPR, no spill).
// ---------------------------------------------------------------------------
__global__ __launch_bounds__(1024) void k_scan(const int* __restrict__ cnt,
                                               int* __restrict__ ptr,
                                               int* __restrict__ cursor)
{
    __shared__ int sh[1024];
    const int t = threadIdx.x;
    const int CH = 49;             // 1024*49 = 50176 >= NN
    const int base = t * CH;
    int sum = 0;
    for (int i = 0; i < CH; i++) {
        int idx = base + i;
        sum += (idx < NN) ? cnt[idx] : 0;
    }
    sh[t] = sum;
    __syncthreads();
    for (int off = 1; off < 1024; off <<= 1) {
        int v = (t >= off) ? sh[t - off] : 0;
        __syncthreads();
        sh[t] += v;
        __syncthreads();
    }
    int run = sh[t] - sum;         // exclusive base for this thread's chunk
    for (int i = 0; i < CH; i++) {
        int idx = base + i;
        if (idx < NN) {
            ptr[idx] = run; cursor[idx] = run;
            run += cnt[idx];       // L2-hot re-read
        }
    }
    if (t == 1023) ptr[NN] = ETOT;
}

// ---------------------------------------------------------------------------
// K5: scatter edges into CSR order; fused: compute ex = exp(leaky(a_s+a_d))
// per head and store in CSR slot (kills the old z-atomics pass entirely).
// ---------------------------------------------------------------------------
__global__ __launch_bounds__(256) void k_scatter(const int* __restrict__ ei,
                                                 const float* __restrict__ a_s,
                                                 const float* __restrict__ a_d,
                                                 int* __restrict__ cursor,
                                                 int* __restrict__ csr_src,
                                                 float* __restrict__ csr_ex)
{
    const int e = blockIdx.x * 256 + threadIdx.x;
    if (e >= ETOT) return;
    int s, d;
    if (e < E_RAW) { s = ei[e]; d = ei[E_RAW + e]; } else { s = e - E_RAW; d = s; }
    int pos = atomicAdd(&cursor[d], 1);
    csr_src[pos] = s;
    float4 as = *(const float4*)&a_s[s * 4];
    float4 ad = *(const float4*)&a_d[d * 4];
    float4 ex;
    ex.x = __expf(leaky(as.x + ad.x));
    ex.y = __expf(leaky(as.y + ad.y));
    ex.z = __expf(leaky(as.z + ad.z));
    ex.w = __expf(leaky(as.w + ad.w));
    *(float4*)&csr_ex[pos * 4] = ex;
}

// ---------------------------------------------------------------------------
// K6: layer-1 aggregation, wave per dst, lane = channel-within-head.
// Single loop: acc[h] += h1[src]*ex_h, z[h] += ex_h; divide at end.
// FUSED epilogue: +b1, ELU, W2 projection (2 cols), layer-2 logits.
// out1 is never materialized.
// ---------------------------------------------------------------------------
__global__ __launch_bounds__(256) void k_agg1(const int* __restrict__ ptr,
                                              const int* __restrict__ csr_src,
                                              const float* __restrict__ csr_ex,
                                              const float* __restrict__ h1,
                                              const float* __restrict__ b1,
                                              const float* __restrict__ W2,
                                              const float* __restrict__ att_src2,
                                              const float* __restrict__ att_dst2,
                                              float* __restrict__ h2,
                                              float* __restrict__ a_s2,
                                              float* __restrict__ a_d2)
{
    const int lane = threadIdx.x & 63;
    const int n = blockIdx.x * 4 + (threadIdx.x >> 6);
    if (n >= NN) return;
    const int beg = ptr[n], end = ptr[n + 1];
    float acc[4] = {0.f, 0.f, 0.f, 0.f};
    float z[4]   = {0.f, 0.f, 0.f, 0.f};
    for (int j = beg; j < end; j++) {
        float4 ex = *(const float4*)&csr_ex[j * 4];   // wave-broadcast
        int s = csr_src[j];                            // wave-broadcast
        const float* hp = &h1[(size_t)s * FH + lane];  // 4x coalesced 256B
        acc[0] += hp[0]   * ex.x;  z[0] += ex.x;
        acc[1] += hp[64]  * ex.y;  z[1] += ex.y;
        acc[2] += hp[128] * ex.z;  z[2] += ex.z;
        acc[3] += hp[192] * ex.w;  z[3] += ex.w;
    }
    float s0 = 0.f, s1 = 0.f;
#pragma unroll
    for (int h = 0; h < 4; h++) {
        int j = h * 64 + lane;
        float v = acc[h] / z[h] + b1[j];
        v = v > 0.f ? v : expm1f(v);   // ELU
        s0 += v * W2[j * 2 + 0];
        s1 += v * W2[j * 2 + 1];
    }
#pragma unroll
    for (int off = 32; off; off >>= 1) {
        s0 += __shfl_xor(s0, off);
        s1 += __shfl_xor(s1, off);
    }
    if (lane == 0) {
        h2[n * 2 + 0] = s0;
        h2[n * 2 + 1] = s1;
        a_s2[n] = s0 * att_src2[0] + s1 * att_src2[1];
        a_d2[n] = s0 * att_dst2[0] + s1 * att_dst2[1];
    }
}

// ---------------------------------------------------------------------------
// K7: layer-2 aggregation, 16 lanes per dst, single loop; writes d_out.
// ---------------------------------------------------------------------------
__global__ __launch_bounds__(256) void k_agg2(const int* __restrict__ ptr,
                                              const int* __restrict__ csr_src,
                                              const float* __restrict__ a_s2,
                                              const float* __restrict__ a_d2,
                                              const float* __restrict__ h2,
                                              const float* __restrict__ b2,
                                              float* __restrict__ out)
{
    const int l = threadIdx.x & 15;
    const int n = blockIdx.x * 16 + (threadIdx.x >> 4);
    if (n >= NN) return;
    const int beg = ptr[n], end = ptr[n + 1];
    const float ad = a_d2[n];
    float z = 0.f, a0 = 0.f, a1 = 0.f;
    for (int j = beg + l; j < end; j += 16) {
        int s = csr_src[j];
        float ex = __expf(leaky(a_s2[s] + ad));
        z  += ex;
        a0 += h2[s * 2 + 0] * ex;
        a1 += h2[s * 2 + 1] * ex;
    }
#pragma unroll
    for (int off = 8; off; off >>= 1) {
        z  += __shfl_xor(z, off);
        a0 += __shfl_xor(a0, off);
        a1 += __shfl_xor(a1, off);
    }
    if (l == 0) {
        out[n * 2 + 0] = a0 / z + b2[0];
        out[n * 2 + 1] = a1 / z + b2[1];
    }
}

extern "C" void kernel_launch(void* const* d_in, const int* in_sizes, int n_in,
                              void* d_out, int out_size, void* d_ws, size_t ws_size,
                              hipStream_t stream)
{
    const float* x        = (const float*)d_in[0];
    const int*   ei       = (const int*)d_in[1];
    const float* W1       = (const float*)d_in[2];
    const float* att_src1 = (const float*)d_in[3];
    const float* att_dst1 = (const float*)d_in[4];
    const float* b1       = (const float*)d_in[5];
    const float* W2       = (const float*)d_in[6];
    const float* att_src2 = (const float*)d_in[7];
    const float* att_dst2 = (const float*)d_in[8];
    const float* b2       = (const float*)d_in[9];
    float* out = (float*)d_out;

    // --- workspace layout (16B-aligned regions) ---
    int*   cnt     = (int*)d_ws;                     // 50004 (NN+1, padded)
    int*   ptr     = cnt + 50004;                    // 50004
    int*   cursor  = ptr + 50004;                    // 50000
    int*   csr_src = cursor + 50000;                 // 850000
    float* csr_ex  = (float*)(csr_src + ETOT);       // 3,400,000
    float* h1      = csr_ex + (size_t)ETOT * 4;      // 12,800,000
    float* a_s1    = h1 + (size_t)NN * FH;           // 200,000
    float* a_d1    = a_s1 + NN * 4;                  // 200,000
    float* h2      = a_d1 + NN * 4;                  // 100,000
    float* a_s2    = h2 + NN * 2;                    // 50,000
    float* a_d2    = a_s2 + NN;                      // 50,000

    hipMemsetAsync(cnt, 0, (size_t)(NN + 1) * sizeof(int), stream);

    k_gemm1<<<(NN + 63) / 64, 256, 0, stream>>>(x, W1, b1, h1);
    k_att1<<<(NN + 3) / 4, 256, 0, stream>>>(h1, att_src1, att_dst1, a_s1, a_d1);
    k_count<<<(ETOT + 255) / 256, 256, 0, stream>>>(ei, cnt);
    k_scan<<<1, 1024, 0, stream>>>(cnt, ptr, cursor);
    k_scatter<<<(ETOT + 255) / 256, 256, 0, stream>>>(ei, a_s1, a_d1, cursor, csr_src, csr_ex);
    k_agg1<<<(NN + 3) / 4, 256, 0, stream>>>(ptr, csr_src, csr_ex, h1, b1, W2,
                                             att_src2, att_dst2, h2, a_s2, a_d2);
    k_agg2<<<(NN + 15) / 16, 256, 0, stream>>>(ptr, csr_src, a_s2, a_d2, h2, b2, out);
}

// Round 4
// 295.818 us; speedup vs baseline: 3.9341x; 1.7243x over previous
//
#include <hip/hip_runtime.h>

#define NN     50000
#define E_RAW  800000
#define ETOT   (E_RAW + NN)   /* 850000: edges + self loops */
#define FIN    128
#define FH     256            /* HEADS*HID */
#define NEG    0.2f
#define BCAP   64             /* bucket capacity; P(deg>64) ~ 1e-18 for Poisson(16) */

static __device__ __forceinline__ float leaky(float v) { return v > 0.f ? v : NEG * v; }

// RNE float->bf16
static __device__ __forceinline__ unsigned f2bf(float f) {
    unsigned u = __float_as_uint(f);
    unsigned r = u + 0x7fffu + ((u >> 16) & 1u);
    return r >> 16;
}

// ---------------------------------------------------------------------------
// K1: h1 = x @ W1 (no bias pre-aggregation, per reference).
// 64 nodes x 256 cols per 256-thread block, 8x8 reg tile.
// FUSED epilogue: (a) h1 stored as bf16 (gather payload), (b) per-head
// attention logits a_s1/a_d1 reduced in-register (wave h owns head h).
// ---------------------------------------------------------------------------
__global__ __launch_bounds__(256) void k_gemm1(const float* __restrict__ x,
                                               const float* __restrict__ W1,
                                               const float* __restrict__ att_src,
                                               const float* __restrict__ att_dst,
                                               unsigned short* __restrict__ h1b,
                                               float* __restrict__ a_s,
                                               float* __restrict__ a_d)
{
    __shared__ float Ws[32][256];
    __shared__ float Xs[32][64];
    const int t = threadIdx.x;
    const int tnode = t & 7;     // node subtile
    const int tcol  = t >> 3;    // col subtile (head = tcol>>3 = t>>6 = wave id)
    const int n0 = blockIdx.x * 64;

    float acc[8][8];
#pragma unroll
    for (int i = 0; i < 8; i++)
#pragma unroll
        for (int j = 0; j < 8; j++) acc[i][j] = 0.f;

    const int xn = t >> 2;
    const int xc = t & 3;

    for (int kk = 0; kk < FIN; kk += 32) {
#pragma unroll
        for (int i = 0; i < 8; i++) {
            int f4 = t + i * 256;
            int r  = f4 >> 6;
            int c4 = f4 & 63;
            float4 v = *(const float4*)&W1[(kk + r) * FH + c4 * 4];
            *(float4*)&Ws[r][c4 * 4] = v;
        }
        {
            int nn = n0 + xn; if (nn >= NN) nn = NN - 1;
            const float* xp = &x[nn * FIN + kk + xc * 8];
            float4 va = *(const float4*)&xp[0];
            float4 vb = *(const float4*)&xp[4];
            Xs[xc * 8 + 0][xn] = va.x; Xs[xc * 8 + 1][xn] = va.y;
            Xs[xc * 8 + 2][xn] = va.z; Xs[xc * 8 + 3][xn] = va.w;
            Xs[xc * 8 + 4][xn] = vb.x; Xs[xc * 8 + 5][xn] = vb.y;
            Xs[xc * 8 + 6][xn] = vb.z; Xs[xc * 8 + 7][xn] = vb.w;
        }
        __syncthreads();
#pragma unroll
        for (int k = 0; k < 32; k++) {
            float4 wa = *(const float4*)&Ws[k][tcol * 8];
            float4 wb = *(const float4*)&Ws[k][tcol * 8 + 4];
            float4 xa = *(const float4*)&Xs[k][tnode * 8];
            float4 xb = *(const float4*)&Xs[k][tnode * 8 + 4];
            float w[8]  = {wa.x, wa.y, wa.z, wa.w, wb.x, wb.y, wb.z, wb.w};
            float xv[8] = {xa.x, xa.y, xa.z, xa.w, xb.x, xb.y, xb.z, xb.w};
#pragma unroll
            for (int i = 0; i < 8; i++)
#pragma unroll
                for (int j = 0; j < 8; j++) acc[i][j] += xv[i] * w[j];
        }
        __syncthreads();
    }

    // --- epilogue A: bf16 store of the 8x8 tile ---
#pragma unroll
    for (int i = 0; i < 8; i++) {
        int n = n0 + tnode * 8 + i;
        if (n < NN) {
            uint4 p;
            p.x = f2bf(acc[i][0]) | (f2bf(acc[i][1]) << 16);
            p.y = f2bf(acc[i][2]) | (f2bf(acc[i][3]) << 16);
            p.z = f2bf(acc[i][4]) | (f2bf(acc[i][5]) << 16);
            p.w = f2bf(acc[i][6]) | (f2bf(acc[i][7]) << 16);
            *(uint4*)&h1b[(size_t)n * FH + tcol * 8] = p;
        }
    }

    // --- epilogue B: attention logits.  att[j] indexed by global channel. ---
    float asw[8], adw[8];
#pragma unroll
    for (int j = 0; j < 8; j++) {
        asw[j] = att_src[tcol * 8 + j];
        adw[j] = att_dst[tcol * 8 + j];
    }
    float ps[8], pd[8];
#pragma unroll
    for (int i = 0; i < 8; i++) {
        float s = 0.f, d = 0.f;
#pragma unroll
        for (int j = 0; j < 8; j++) { s += acc[i][j] * asw[j]; d += acc[i][j] * adw[j]; }
        ps[i] = s; pd[i] = d;
    }
    // reduce over the 8 lanes (stride 8) holding the same node group & head
#pragma unroll
    for (int m = 8; m <= 32; m <<= 1) {
#pragma unroll
        for (int i = 0; i < 8; i++) {
            ps[i] += __shfl_xor(ps[i], m);
            pd[i] += __shfl_xor(pd[i], m);
        }
    }
    if ((t & 63) < 8) {            // q==0 lane of each (tnode, head)
        int h = t >> 6;            // wave id == head
#pragma unroll
        for (int i = 0; i < 8; i++) {
            int n = n0 + tnode * 8 + i;
            if (n < NN) { a_s[n * 4 + h] = ps[i]; a_d[n * 4 + h] = pd[i]; }
        }
    }
}

// ---------------------------------------------------------------------------
// K2: bucket scatter (self-counting, no scan).  slot = dst*64 + pos.
// Fused ex = exp(leaky(a_s[src]+a_d[dst])) per head.
// ---------------------------------------------------------------------------
__global__ __launch_bounds__(256) void k_scatter(const int* __restrict__ ei,
                                                 const float* __restrict__ a_s,
                                                 const float* __restrict__ a_d,
                                                 int* __restrict__ cnt,
                                                 int* __restrict__ csr_src,
                                                 float4* __restrict__ csr_ex)
{
    const int e = blockIdx.x * 256 + threadIdx.x;
    if (e >= ETOT) return;
    int s, d;
    if (e < E_RAW) { s = ei[e]; d = ei[E_RAW + e]; } else { s = e - E_RAW; d = s; }
    int pos = atomicAdd(&cnt[d], 1);
    if (pos >= BCAP) return;       // statistically unreachable
    int slot = (d << 6) + pos;
    csr_src[slot] = s;
    float4 as = *(const float4*)&a_s[s * 4];
    float4 ad = *(const float4*)&a_d[d * 4];
    float4 ex;
    ex.x = __expf(leaky(as.x + ad.x));
    ex.y = __expf(leaky(as.y + ad.y));
    ex.z = __expf(leaky(as.z + ad.z));
    ex.w = __expf(leaky(as.w + ad.w));
    csr_ex[slot] = ex;
}

// ---------------------------------------------------------------------------
// K3: layer-1 aggregation, wave per dst.  bf16 pair-packed gather:
// lane l owns channels {2l,2l+1} (heads 0/1) and {128+2l,129+2l} (heads 2/3)
// -> 2x 256B transactions per edge.  Register accumulate; divide by z at end.
// FUSED: +b1, ELU, W2 projection, layer-2 logits.  out1 never materialized.
// ---------------------------------------------------------------------------
__global__ __launch_bounds__(256) void k_agg1(const int* __restrict__ cnt,
                                              const int* __restrict__ csr_src,
                                              const float4* __restrict__ csr_ex,
                                              const unsigned* __restrict__ h1u,
                                              const float* __restrict__ b1,
                                              const float* __restrict__ W2,
                                              const float* __restrict__ att_src2,
                                              const float* __restrict__ att_dst2,
                                              float* __restrict__ h2,
                                              float* __restrict__ a_s2,
                                              float* __restrict__ a_d2)
{
    const int lane = threadIdx.x & 63;
    const int n = blockIdx.x * 4 + (threadIdx.x >> 6);
    if (n >= NN) return;
    int m = cnt[n]; if (m > BCAP) m = BCAP;
    const int base = n << 6;
    const int hs = lane >> 5;      // head-half selector
    float a0 = 0.f, a1 = 0.f, a2 = 0.f, a3 = 0.f, zlo = 0.f, zhi = 0.f;
    for (int j = 0; j < m; j++) {
        float4 ex = csr_ex[base + j];          // wave-broadcast 16B
        int s = csr_src[base + j];             // wave-broadcast 4B
        float exA = hs ? ex.y : ex.x;
        float exB = hs ? ex.w : ex.z;
        const unsigned* hp = &h1u[(size_t)s * 128 + lane];
        unsigned w0 = hp[0];                   // ch 2l, 2l+1
        unsigned w1 = hp[64];                  // ch 128+2l, 129+2l
        float v00 = __uint_as_float(w0 << 16);
        float v01 = __uint_as_float(w0 & 0xffff0000u);
        float v10 = __uint_as_float(w1 << 16);
        float v11 = __uint_as_float(w1 & 0xffff0000u);
        a0 += v00 * exA; a1 += v01 * exA;
        a2 += v10 * exB; a3 += v11 * exB;
        zlo += exA; zhi += exB;
    }
    const int j0 = lane * 2, j2 = 128 + lane * 2;
    float v0 = a0 / zlo + b1[j0];
    float v1 = a1 / zlo + b1[j0 + 1];
    float v2 = a2 / zhi + b1[j2];
    float v3 = a3 / zhi + b1[j2 + 1];
    v0 = v0 > 0.f ? v0 : expm1f(v0);
    v1 = v1 > 0.f ? v1 : expm1f(v1);
    v2 = v2 > 0.f ? v2 : expm1f(v2);
    v3 = v3 > 0.f ? v3 : expm1f(v3);
    float s0 = v0 * W2[j0 * 2]     + v1 * W2[(j0 + 1) * 2]
             + v2 * W2[j2 * 2]     + v3 * W2[(j2 + 1) * 2];
    float s1 = v0 * W2[j0 * 2 + 1] + v1 * W2[(j0 + 1) * 2 + 1]
             + v2 * W2[j2 * 2 + 1] + v3 * W2[(j2 + 1) * 2 + 1];
#pragma unroll
    for (int off = 32; off; off >>= 1) {
        s0 += __shfl_xor(s0, off);
        s1 += __shfl_xor(s1, off);
    }
    if (lane == 0) {
        h2[n * 2 + 0] = s0;
        h2[n * 2 + 1] = s1;
        a_s2[n] = s0 * att_src2[0] + s1 * att_src2[1];
        a_d2[n] = s0 * att_dst2[0] + s1 * att_dst2[1];
    }
}

// ---------------------------------------------------------------------------
// K4: layer-2 aggregation, 16 lanes per dst; writes d_out.
// ---------------------------------------------------------------------------
__global__ __launch_bounds__(256) void k_agg2(const int* __restrict__ cnt,
                                              const int* __restrict__ csr_src,
                                              const float* __restrict__ a_s2,
                                              const float* __restrict__ a_d2,
                                              const float* __restrict__ h2,
                                              const float* __restrict__ b2,
                                              float* __restrict__ out)
{
    const int l = threadIdx.x & 15;
    const int n = blockIdx.x * 16 + (threadIdx.x >> 4);
    if (n >= NN) return;
    int m = cnt[n]; if (m > BCAP) m = BCAP;
    const int base = n << 6;
    const float ad = a_d2[n];
    float z = 0.f, a0 = 0.f, a1 = 0.f;
    for (int j = l; j < m; j += 16) {
        int s = csr_src[base + j];
        float ex = __expf(leaky(a_s2[s] + ad));
        z  += ex;
        a0 += h2[s * 2 + 0] * ex;
        a1 += h2[s * 2 + 1] * ex;
    }
#pragma unroll
    for (int off = 8; off; off >>= 1) {
        z  += __shfl_xor(z, off);
        a0 += __shfl_xor(a0, off);
        a1 += __shfl_xor(a1, off);
    }
    if (l == 0) {
        out[n * 2 + 0] = a0 / z + b2[0];
        out[n * 2 + 1] = a1 / z + b2[1];
    }
}

extern "C" void kernel_launch(void* const* d_in, const int* in_sizes, int n_in,
                              void* d_out, int out_size, void* d_ws, size_t ws_size,
                              hipStream_t stream)
{
    const float* x        = (const float*)d_in[0];
    const int*   ei       = (const int*)d_in[1];
    const float* W1       = (const float*)d_in[2];
    const float* att_src1 = (const float*)d_in[3];
    const float* att_dst1 = (const float*)d_in[4];
    const float* b1       = (const float*)d_in[5];
    const float* W2       = (const float*)d_in[6];
    const float* att_src2 = (const float*)d_in[7];
    const float* att_dst2 = (const float*)d_in[8];
    const float* b2       = (const float*)d_in[9];
    float* out = (float*)d_out;

    // --- workspace layout (all regions 16B aligned) ---
    float4* csr_ex = (float4*)d_ws;                          // 50000*64*16B = 51.2 MB
    int*    csr_src = (int*)(csr_ex + (size_t)NN * BCAP);    // 12.8 MB
    unsigned short* h1b = (unsigned short*)(csr_src + (size_t)NN * BCAP); // 25.6 MB
    int*    cnt   = (int*)(h1b + (size_t)NN * FH);           // 200 KB
    float*  a_s1  = (float*)(cnt + NN);                      // 800 KB
    float*  a_d1  = a_s1 + (size_t)NN * 4;                   // 800 KB
    float*  h2    = a_d1 + (size_t)NN * 4;                   // 400 KB
    float*  a_s2  = h2 + (size_t)NN * 2;                     // 200 KB
    float*  a_d2  = a_s2 + NN;                               // 200 KB

    hipMemsetAsync(cnt, 0, (size_t)NN * sizeof(int), stream);

    k_gemm1<<<(NN + 63) / 64, 256, 0, stream>>>(x, W1, att_src1, att_dst1, h1b, a_s1, a_d1);
    k_scatter<<<(ETOT + 255) / 256, 256, 0, stream>>>(ei, a_s1, a_d1, cnt, csr_src, csr_ex);
    k_agg1<<<(NN + 3) / 4, 256, 0, stream>>>(cnt, csr_src, csr_ex, (const unsigned*)h1b,
                                             b1, W2, att_src2, att_dst2, h2, a_s2, a_d2);
    k_agg2<<<(NN + 15) / 16, 256, 0, stream>>>(cnt, csr_src, a_s2, a_d2, h2, b2, out);
}

// Round 5
// 286.854 us; speedup vs baseline: 4.0570x; 1.0312x over previous
//
#include <hip/hip_runtime.h>

#define NN     50000
#define E_RAW  800000
#define ETOT   (E_RAW + NN)   /* 850000: edges + self loops */
#define FIN    128
#define FH     256            /* HEADS*HID */
#define NEG    0.2f
#define BCAP   64             /* bucket capacity; P(deg>64) ~ 1e-18 for Poisson(16) */

typedef __attribute__((ext_vector_type(8))) short s16x8;
typedef __attribute__((ext_vector_type(4))) float f32x4;

static __device__ __forceinline__ float leaky(float v) { return v > 0.f ? v : NEG * v; }

// RNE float->bf16
static __device__ __forceinline__ unsigned short f2bf(float f) {
    unsigned u = __float_as_uint(f);
    unsigned r = u + 0x7fffu + ((u >> 16) & 1u);
    return (unsigned short)(r >> 16);
}

// ---------------------------------------------------------------------------
// K1: h1 = x @ W1 via MFMA bf16.  64 nodes x 256 cols per block, 4 waves;
// wave w owns cols [64w,64w+64) == head w.  LDS: Wt[col][k] bf16 (transposed,
// pad 136 for 16B-aligned b128 reads), Xt[node][k] bf16.
// A frag: A[m=lane&15][k=quad*8+j] (verified m120); B frag mirrors (m97 B^T).
// C/D: col=lane&15, row=quad*4+reg (verified m89/m91).
// Epilogue: per-head logits from fp32 acc (wave==head, 16-lane shfl reduce);
// h1b bf16 stores via LDS round-trip (Ot aliases Wt) for coalescing.
// ---------------------------------------------------------------------------
__global__ __launch_bounds__(256) void k_gemm1(const float* __restrict__ x,
                                               const float* __restrict__ W1,
                                               const float* __restrict__ att_src,
                                               const float* __restrict__ att_dst,
                                               unsigned short* __restrict__ h1b,
                                               float* __restrict__ a_s,
                                               float* __restrict__ a_d)
{
    __shared__ unsigned short Wt[256][136];
    __shared__ unsigned short Xt[64][136];
    const int t    = threadIdx.x;
    const int w    = t >> 6;         // wave id == head
    const int lane = t & 63;
    const int li   = lane & 15;      // m/n within 16-tile
    const int q8   = (lane >> 4) * 8;
    const int quad = lane >> 4;
    const int n0   = blockIdx.x * 64;

    // --- stage W1 (fp32 [k][col] -> bf16 Wt[col][k]) ---
    {
        const int c4 = (t & 63) * 4;
        for (int r = t >> 6; r < FIN; r += 4) {
            float4 v = *(const float4*)&W1[r * FH + c4];
            Wt[c4 + 0][r] = f2bf(v.x);
            Wt[c4 + 1][r] = f2bf(v.y);
            Wt[c4 + 2][r] = f2bf(v.z);
            Wt[c4 + 3][r] = f2bf(v.w);
        }
    }
    // --- stage x (fp32 -> bf16 Xt[node][k]) ---
    {
        const int node_l = t >> 2;
        const int k0 = (t & 3) * 32;
        int nn = n0 + node_l; if (nn >= NN) nn = NN - 1;
        const float* xp = &x[(size_t)nn * FIN + k0];
        unsigned short* xd = &Xt[node_l][k0];
#pragma unroll
        for (int i = 0; i < 8; i++) {
            float4 v = *(const float4*)&xp[i * 4];
            xd[i * 4 + 0] = f2bf(v.x);
            xd[i * 4 + 1] = f2bf(v.y);
            xd[i * 4 + 2] = f2bf(v.z);
            xd[i * 4 + 3] = f2bf(v.w);
        }
    }
    __syncthreads();

    // --- MFMA K-loop ---
    f32x4 acc[4][4];
#pragma unroll
    for (int i = 0; i < 4; i++)
#pragma unroll
        for (int j = 0; j < 4; j++) acc[i][j] = (f32x4){0.f, 0.f, 0.f, 0.f};

    for (int kk = 0; kk < FIN; kk += 32) {
        s16x8 af[4], bf[4];
#pragma unroll
        for (int m16 = 0; m16 < 4; m16++)
            af[m16] = *(const s16x8*)&Xt[m16 * 16 + li][kk + q8];
#pragma unroll
        for (int n16 = 0; n16 < 4; n16++)
            bf[n16] = *(const s16x8*)&Wt[w * 64 + n16 * 16 + li][kk + q8];
#pragma unroll
        for (int m16 = 0; m16 < 4; m16++)
#pragma unroll
            for (int n16 = 0; n16 < 4; n16++)
                acc[m16][n16] = __builtin_amdgcn_mfma_f32_16x16x32_bf16(
                    af[m16], bf[n16], acc[m16][n16], 0, 0, 0);
    }

    // --- epilogue A: per-head attention logits from fp32 acc ---
    {
        float as_c[4], ad_c[4];
#pragma unroll
        for (int n16 = 0; n16 < 4; n16++) {
            int col = w * 64 + n16 * 16 + li;
            as_c[n16] = att_src[col];
            ad_c[n16] = att_dst[col];
        }
#pragma unroll
        for (int m16 = 0; m16 < 4; m16++) {
            float ps[4], pd[4];
#pragma unroll
            for (int reg = 0; reg < 4; reg++) {
                float s = 0.f, d = 0.f;
#pragma unroll
                for (int n16 = 0; n16 < 4; n16++) {
                    s += acc[m16][n16][reg] * as_c[n16];
                    d += acc[m16][n16][reg] * ad_c[n16];
                }
                ps[reg] = s; pd[reg] = d;
            }
#pragma unroll
            for (int off = 1; off < 16; off <<= 1) {
#pragma unroll
                for (int reg = 0; reg < 4; reg++) {
                    ps[reg] += __shfl_xor(ps[reg], off);
                    pd[reg] += __shfl_xor(pd[reg], off);
                }
            }
            if (li == 0) {
#pragma unroll
                for (int reg = 0; reg < 4; reg++) {
                    int node = n0 + m16 * 16 + quad * 4 + reg;
                    if (node < NN) {
                        a_s[node * 4 + w] = ps[reg];
                        a_d[node * 4 + w] = pd[reg];
                    }
                }
            }
        }
    }

    // --- epilogue B: bf16 store via LDS round-trip (Ot aliases Wt) ---
    __syncthreads();               // all waves done reading Wt
    unsigned short* Ot = &Wt[0][0];  // [64][256] bf16 tile
#pragma unroll
    for (int m16 = 0; m16 < 4; m16++)
#pragma unroll
        for (int n16 = 0; n16 < 4; n16++)
#pragma unroll
            for (int reg = 0; reg < 4; reg++)
                Ot[(m16 * 16 + quad * 4 + reg) * FH + w * 64 + n16 * 16 + li] =
                    f2bf(acc[m16][n16][reg]);
    __syncthreads();
    {
        const int node_l = t >> 2;
        const int c0 = (t & 3) * 64;
        int node = n0 + node_l;
        if (node < NN) {
#pragma unroll
            for (int i = 0; i < 8; i++)
                *(uint4*)&h1b[(size_t)node * FH + c0 + i * 8] =
                    *(const uint4*)&Ot[node_l * FH + c0 + i * 8];
        }
    }
}

// ---------------------------------------------------------------------------
// K2: bucket scatter (self-counting).  slot = dst*64 + pos.
// Fused ex = exp(leaky(a_s[src]+a_d[dst])) per head.
// ---------------------------------------------------------------------------
__global__ __launch_bounds__(256) void k_scatter(const int* __restrict__ ei,
                                                 const float* __restrict__ a_s,
                                                 const float* __restrict__ a_d,
                                                 int* __restrict__ cnt,
                                                 int* __restrict__ csr_src,
                                                 float4* __restrict__ csr_ex)
{
    const int e = blockIdx.x * 256 + threadIdx.x;
    if (e >= ETOT) return;
    int s, d;
    if (e < E_RAW) { s = ei[e]; d = ei[E_RAW + e]; } else { s = e - E_RAW; d = s; }
    int pos = atomicAdd(&cnt[d], 1);
    if (pos >= BCAP) return;       // statistically unreachable
    int slot = (d << 6) + pos;
    csr_src[slot] = s;
    float4 as = *(const float4*)&a_s[s * 4];
    float4 ad = *(const float4*)&a_d[d * 4];
    float4 ex;
    ex.x = __expf(leaky(as.x + ad.x));
    ex.y = __expf(leaky(as.y + ad.y));
    ex.z = __expf(leaky(as.z + ad.z));
    ex.w = __expf(leaky(as.w + ad.w));
    csr_ex[slot] = ex;
}

// ---------------------------------------------------------------------------
// K3: layer-1 aggregation.  TWO waves per dst (edge parity split) to halve
// the serial gather chain; explicit next-edge prefetch; LDS combine.
// lane l owns channels {2l,2l+1} + {128+2l,129+2l}; divide by z at end.
// FUSED: +b1, ELU, W2 projection, layer-2 logits.
// ---------------------------------------------------------------------------
__global__ __launch_bounds__(256) void k_agg1(const int* __restrict__ cnt,
                                              const int* __restrict__ csr_src,
                                              const float4* __restrict__ csr_ex,
                                              const unsigned* __restrict__ h1u,
                                              const float* __restrict__ b1,
                                              const float* __restrict__ W2,
                                              const float* __restrict__ att_src2,
                                              const float* __restrict__ att_dst2,
                                              float* __restrict__ h2,
                                              float* __restrict__ a_s2,
                                              float* __restrict__ a_d2)
{
    __shared__ float sh[2][6][64];
    const int t = threadIdx.x;
    const int lane = t & 63;
    const int half = (t >> 6) & 1;
    const int nb = t >> 7;               // node-in-block 0..1
    const int n = blockIdx.x * 2 + nb;   // NN even, grid exact: n < NN always
    int m = cnt[n]; if (m > BCAP) m = BCAP;
    const int base = n << 6;
    const int hs = lane >> 5;
    float a0 = 0.f, a1 = 0.f, a2 = 0.f, a3 = 0.f, zlo = 0.f, zhi = 0.f;

    int j = half;
    if (j < m) {
        int s_cur = csr_src[base + j];
        float4 e_cur = csr_ex[base + j];
        while (true) {
            int jn = j + 2;
            bool more = jn < m;
            int s_nxt = s_cur; float4 e_nxt = e_cur;
            if (more) { s_nxt = csr_src[base + jn]; e_nxt = csr_ex[base + jn]; }
            float exA = hs ? e_cur.y : e_cur.x;
            float exB = hs ? e_cur.w : e_cur.z;
            const unsigned* hp = &h1u[(size_t)s_cur * 128 + lane];
            unsigned w0 = hp[0];
            unsigned w1 = hp[64];
            float v00 = __uint_as_float(w0 << 16);
            float v01 = __uint_as_float(w0 & 0xffff0000u);
            float v10 = __uint_as_float(w1 << 16);
            float v11 = __uint_as_float(w1 & 0xffff0000u);
            a0 += v00 * exA; a1 += v01 * exA;
            a2 += v10 * exB; a3 += v11 * exB;
            zlo += exA; zhi += exB;
            if (!more) break;
            s_cur = s_nxt; e_cur = e_nxt; j = jn;
        }
    }
    if (half == 1) {
        sh[nb][0][lane] = a0; sh[nb][1][lane] = a1; sh[nb][2][lane] = a2;
        sh[nb][3][lane] = a3; sh[nb][4][lane] = zlo; sh[nb][5][lane] = zhi;
    }
    __syncthreads();
    if (half == 1) return;
    a0 += sh[nb][0][lane]; a1 += sh[nb][1][lane]; a2 += sh[nb][2][lane];
    a3 += sh[nb][3][lane]; zlo += sh[nb][4][lane]; zhi += sh[nb][5][lane];

    const int j0 = lane * 2, j2 = 128 + lane * 2;
    float v0 = a0 / zlo + b1[j0];
    float v1 = a1 / zlo + b1[j0 + 1];
    float v2 = a2 / zhi + b1[j2];
    float v3 = a3 / zhi + b1[j2 + 1];
    v0 = v0 > 0.f ? v0 : expm1f(v0);
    v1 = v1 > 0.f ? v1 : expm1f(v1);
    v2 = v2 > 0.f ? v2 : expm1f(v2);
    v3 = v3 > 0.f ? v3 : expm1f(v3);
    float s0 = v0 * W2[j0 * 2]     + v1 * W2[(j0 + 1) * 2]
             + v2 * W2[j2 * 2]     + v3 * W2[(j2 + 1) * 2];
    float s1 = v0 * W2[j0 * 2 + 1] + v1 * W2[(j0 + 1) * 2 + 1]
             + v2 * W2[j2 * 2 + 1] + v3 * W2[(j2 + 1) * 2 + 1];
#pragma unroll
    for (int off = 32; off; off >>= 1) {
        s0 += __shfl_xor(s0, off);
        s1 += __shfl_xor(s1, off);
    }
    if (lane == 0) {
        h2[n * 2 + 0] = s0;
        h2[n * 2 + 1] = s1;
        a_s2[n] = s0 * att_src2[0] + s1 * att_src2[1];
        a_d2[n] = s0 * att_dst2[0] + s1 * att_dst2[1];
    }
}

// ---------------------------------------------------------------------------
// K4: layer-2 aggregation, 16 lanes per dst; writes d_out.
// ---------------------------------------------------------------------------
__global__ __launch_bounds__(256) void k_agg2(const int* __restrict__ cnt,
                                              const int* __restrict__ csr_src,
                                              const float* __restrict__ a_s2,
                                              const float* __restrict__ a_d2,
                                              const float* __restrict__ h2,
                                              const float* __restrict__ b2,
                                              float* __restrict__ out)
{
    const int l = threadIdx.x & 15;
    const int n = blockIdx.x * 16 + (threadIdx.x >> 4);
    if (n >= NN) return;
    int m = cnt[n]; if (m > BCAP) m = BCAP;
    const int base = n << 6;
    const float ad = a_d2[n];
    float z = 0.f, a0 = 0.f, a1 = 0.f;
    for (int j = l; j < m; j += 16) {
        int s = csr_src[base + j];
        float ex = __expf(leaky(a_s2[s] + ad));
        z  += ex;
        a0 += h2[s * 2 + 0] * ex;
        a1 += h2[s * 2 + 1] * ex;
    }
#pragma unroll
    for (int off = 8; off; off >>= 1) {
        z  += __shfl_xor(z, off);
        a0 += __shfl_xor(a0, off);
        a1 += __shfl_xor(a1, off);
    }
    if (l == 0) {
        out[n * 2 + 0] = a0 / z + b2[0];
        out[n * 2 + 1] = a1 / z + b2[1];
    }
}

extern "C" void kernel_launch(void* const* d_in, const int* in_sizes, int n_in,
                              void* d_out, int out_size, void* d_ws, size_t ws_size,
                              hipStream_t stream)
{
    const float* x        = (const float*)d_in[0];
    const int*   ei       = (const int*)d_in[1];
    const float* W1       = (const float*)d_in[2];
    const float* att_src1 = (const float*)d_in[3];
    const float* att_dst1 = (const float*)d_in[4];
    const float* b1       = (const float*)d_in[5];
    const float* W2       = (const float*)d_in[6];
    const float* att_src2 = (const float*)d_in[7];
    const float* att_dst2 = (const float*)d_in[8];
    const float* b2       = (const float*)d_in[9];
    float* out = (float*)d_out;

    // --- workspace layout (all regions 16B aligned) ---
    float4* csr_ex = (float4*)d_ws;                          // 51.2 MB
    int*    csr_src = (int*)(csr_ex + (size_t)NN * BCAP);    // 12.8 MB
    unsigned short* h1b = (unsigned short*)(csr_src + (size_t)NN * BCAP); // 25.6 MB
    int*    cnt   = (int*)(h1b + (size_t)NN * FH);           // 200 KB
    float*  a_s1  = (float*)(cnt + NN);                      // 800 KB
    float*  a_d1  = a_s1 + (size_t)NN * 4;                   // 800 KB
    float*  h2    = a_d1 + (size_t)NN * 4;                   // 400 KB
    float*  a_s2  = h2 + (size_t)NN * 2;                     // 200 KB
    float*  a_d2  = a_s2 + NN;                               // 200 KB

    hipMemsetAsync(cnt, 0, (size_t)NN * sizeof(int), stream);

    k_gemm1<<<(NN + 63) / 64, 256, 0, stream>>>(x, W1, att_src1, att_dst1, h1b, a_s1, a_d1);
    k_scatter<<<(ETOT + 255) / 256, 256, 0, stream>>>(ei, a_s1, a_d1, cnt, csr_src, csr_ex);
    k_agg1<<<NN / 2, 256, 0, stream>>>(cnt, csr_src, csr_ex, (const unsigned*)h1b,
                                       b1, W2, att_src2, att_dst2, h2, a_s2, a_d2);
    k_agg2<<<(NN + 15) / 16, 256, 0, stream>>>(cnt, csr_src, a_s2, a_d2, h2, b2, out);
}

// Round 6
// 243.171 us; speedup vs baseline: 4.7858x; 1.1796x over previous
//
#include <hip/hip_runtime.h>

#define NN     50000
#define E_RAW  800000
#define ETOT   (E_RAW + NN)   /* 850000: edges + self loops */
#define FIN    128
#define FH     256            /* HEADS*HID */
#define NEG    0.2f
#define BCAP   64             /* bucket capacity; P(deg>64) ~ 1e-18 for Poisson(16) */

typedef __attribute__((ext_vector_type(8))) short s16x8;
typedef __attribute__((ext_vector_type(4))) float f32x4;

static __device__ __forceinline__ float leaky(float v) { return v > 0.f ? v : NEG * v; }

// RNE float->bf16
static __device__ __forceinline__ unsigned short f2bf(float f) {
    unsigned u = __float_as_uint(f);
    unsigned r = u + 0x7fffu + ((u >> 16) & 1u);
    return (unsigned short)(r >> 16);
}

// ---------------------------------------------------------------------------
// K0: prep — (a) W1 fp32 [k][col] -> bf16 transposed Wt_bf[col][k] (done once,
// hoisted out of all 782 gemm blocks); (b) zero cnt (replaces memset dispatch).
// ---------------------------------------------------------------------------
__global__ __launch_bounds__(256) void k_prep(const float* __restrict__ W1,
                                              unsigned short* __restrict__ Wt_bf,
                                              int* __restrict__ cnt)
{
    const int b = blockIdx.x, t = threadIdx.x;
    if (b < FIN) Wt_bf[t * FIN + b] = f2bf(W1[b * FH + t]);
    int idx = b * 256 + t;
    if (idx < NN) cnt[idx] = 0;
}

// ---------------------------------------------------------------------------
// K1: h1 = x @ W1 via MFMA bf16.  64 nodes x 256 cols per block, 4 waves;
// wave w owns cols [64w,64w+64) == head w.  Wt staged from preconverted bf16.
// A frag: A[m=lane&15][k=quad*8+j]; C/D: col=lane&15, row=quad*4+reg.
// Epilogue: per-head logits from fp32 acc; h1b bf16 via LDS round-trip.
// ---------------------------------------------------------------------------
__global__ __launch_bounds__(256) void k_gemm1(const float* __restrict__ x,
                                               const unsigned short* __restrict__ Wt_bf,
                                               const float* __restrict__ att_src,
                                               const float* __restrict__ att_dst,
                                               unsigned short* __restrict__ h1b,
                                               float* __restrict__ a_s,
                                               float* __restrict__ a_d)
{
    __shared__ unsigned short Wt[256][136];
    __shared__ unsigned short Xt[64][136];
    const int t    = threadIdx.x;
    const int w    = t >> 6;         // wave id == head
    const int lane = t & 63;
    const int li   = lane & 15;
    const int q8   = (lane >> 4) * 8;
    const int quad = lane >> 4;
    const int n0   = blockIdx.x * 64;

    // --- stage Wt (straight bf16 copy, 4096 uint4) ---
#pragma unroll
    for (int i = 0; i < 16; i++) {
        int f = t + i * 256;
        int row = f >> 4, c16 = f & 15;
        *(uint4*)&Wt[row][c16 * 8] = *(const uint4*)&Wt_bf[row * FIN + c16 * 8];
    }
    // --- stage x (fp32 -> bf16 Xt[node][k]) ---
    {
        const int node_l = t >> 2;
        const int k0 = (t & 3) * 32;
        int nn = n0 + node_l; if (nn >= NN) nn = NN - 1;
        const float* xp = &x[(size_t)nn * FIN + k0];
        unsigned short* xd = &Xt[node_l][k0];
#pragma unroll
        for (int i = 0; i < 8; i++) {
            float4 v = *(const float4*)&xp[i * 4];
            xd[i * 4 + 0] = f2bf(v.x);
            xd[i * 4 + 1] = f2bf(v.y);
            xd[i * 4 + 2] = f2bf(v.z);
            xd[i * 4 + 3] = f2bf(v.w);
        }
    }
    __syncthreads();

    // --- MFMA K-loop ---
    f32x4 acc[4][4];
#pragma unroll
    for (int i = 0; i < 4; i++)
#pragma unroll
        for (int j = 0; j < 4; j++) acc[i][j] = (f32x4){0.f, 0.f, 0.f, 0.f};

    for (int kk = 0; kk < FIN; kk += 32) {
        s16x8 af[4], bf[4];
#pragma unroll
        for (int m16 = 0; m16 < 4; m16++)
            af[m16] = *(const s16x8*)&Xt[m16 * 16 + li][kk + q8];
#pragma unroll
        for (int n16 = 0; n16 < 4; n16++)
            bf[n16] = *(const s16x8*)&Wt[w * 64 + n16 * 16 + li][kk + q8];
#pragma unroll
        for (int m16 = 0; m16 < 4; m16++)
#pragma unroll
            for (int n16 = 0; n16 < 4; n16++)
                acc[m16][n16] = __builtin_amdgcn_mfma_f32_16x16x32_bf16(
                    af[m16], bf[n16], acc[m16][n16], 0, 0, 0);
    }

    // --- epilogue A: per-head attention logits from fp32 acc ---
    {
        float as_c[4], ad_c[4];
#pragma unroll
        for (int n16 = 0; n16 < 4; n16++) {
            int col = w * 64 + n16 * 16 + li;
            as_c[n16] = att_src[col];
            ad_c[n16] = att_dst[col];
        }
#pragma unroll
        for (int m16 = 0; m16 < 4; m16++) {
            float ps[4], pd[4];
#pragma unroll
            for (int reg = 0; reg < 4; reg++) {
                float s = 0.f, d = 0.f;
#pragma unroll
                for (int n16 = 0; n16 < 4; n16++) {
                    s += acc[m16][n16][reg] * as_c[n16];
                    d += acc[m16][n16][reg] * ad_c[n16];
                }
                ps[reg] = s; pd[reg] = d;
            }
#pragma unroll
            for (int off = 1; off < 16; off <<= 1) {
#pragma unroll
                for (int reg = 0; reg < 4; reg++) {
                    ps[reg] += __shfl_xor(ps[reg], off);
                    pd[reg] += __shfl_xor(pd[reg], off);
                }
            }
            if (li == 0) {
#pragma unroll
                for (int reg = 0; reg < 4; reg++) {
                    int node = n0 + m16 * 16 + quad * 4 + reg;
                    if (node < NN) {
                        a_s[node * 4 + w] = ps[reg];
                        a_d[node * 4 + w] = pd[reg];
                    }
                }
            }
        }
    }

    // --- epilogue B: bf16 store via LDS round-trip (Ot aliases Wt) ---
    __syncthreads();
    unsigned short* Ot = &Wt[0][0];  // [64][256] bf16 tile
#pragma unroll
    for (int m16 = 0; m16 < 4; m16++)
#pragma unroll
        for (int n16 = 0; n16 < 4; n16++)
#pragma unroll
            for (int reg = 0; reg < 4; reg++)
                Ot[(m16 * 16 + quad * 4 + reg) * FH + w * 64 + n16 * 16 + li] =
                    f2bf(acc[m16][n16][reg]);
    __syncthreads();
    {
        const int node_l = t >> 2;
        const int c0 = (t & 3) * 64;
        int node = n0 + node_l;
        if (node < NN) {
#pragma unroll
            for (int i = 0; i < 8; i++)
                *(uint4*)&h1b[(size_t)node * FH + c0 + i * 8] =
                    *(const uint4*)&Ot[node_l * FH + c0 + i * 8];
        }
    }
}

// ---------------------------------------------------------------------------
// K2: bucket scatter, minimal: read edge, atomic slot, write src index.
// (ex recomputed in k_agg1 — no csr_ex materialization.)
// ---------------------------------------------------------------------------
__global__ __launch_bounds__(256) void k_scatter(const int* __restrict__ ei,
                                                 int* __restrict__ cnt,
                                                 int* __restrict__ csr_src)
{
    const int e = blockIdx.x * 256 + threadIdx.x;
    if (e >= ETOT) return;
    int s, d;
    if (e < E_RAW) { s = ei[e]; d = ei[E_RAW + e]; } else { s = e - E_RAW; d = s; }
    int pos = atomicAdd(&cnt[d], 1);
    if (pos >= BCAP) return;       // statistically unreachable
    csr_src[(d << 6) + pos] = s;
}

// ---------------------------------------------------------------------------
// K3: layer-1 aggregation.  ONE wave per dst; lane l owns channels 4l..4l+3
// (head = l>>4, uniform per lane).  Per edge: 1x 8B gather of h1 row slice,
// per-lane a_s1[s*4+h] load, in-loop exp.  unroll 4 => 4 gathers in flight.
// FUSED: /z, +b1, ELU, W2 projection, layer-2 logits -> nd4 packed.
// ---------------------------------------------------------------------------
__global__ __launch_bounds__(256) void k_agg1(const int* __restrict__ cnt,
                                              const int* __restrict__ csr_src,
                                              const float* __restrict__ a_s1,
                                              const float* __restrict__ a_d1,
                                              const unsigned short* __restrict__ h1b,
                                              const float* __restrict__ b1,
                                              const float* __restrict__ W2,
                                              const float* __restrict__ att_src2,
                                              const float* __restrict__ att_dst2,
                                              float4* __restrict__ nd4)
{
    const int lane = threadIdx.x & 63;
    const int n = blockIdx.x * 4 + (threadIdx.x >> 6);
    if (n >= NN) return;
    int m = cnt[n]; if (m > BCAP) m = BCAP;
    const int base = n << 6;
    const int h = lane >> 4;                     // head of this lane
    const float ad_h = a_d1[n * 4 + h];
    float acc0 = 0.f, acc1 = 0.f, acc2 = 0.f, acc3 = 0.f, z = 0.f;
    const int* sp = &csr_src[base];
#pragma unroll 4
    for (int j = 0; j < m; j++) {
        int s = sp[j];                           // wave-uniform 4B
        float as_h = a_s1[s * 4 + h];            // 4 addrs/wave, L2-hot
        float ex = __expf(leaky(as_h + ad_h));
        unsigned long long wv =
            *(const unsigned long long*)(h1b + (size_t)s * FH + lane * 4);
        unsigned lo = (unsigned)wv, hi = (unsigned)(wv >> 32);
        acc0 += __uint_as_float(lo << 16) * ex;
        acc1 += __uint_as_float(lo & 0xffff0000u) * ex;
        acc2 += __uint_as_float(hi << 16) * ex;
        acc3 += __uint_as_float(hi & 0xffff0000u) * ex;
        z += ex;
    }
    const int c0 = lane * 4;
    float4 bb = *(const float4*)&b1[c0];
    float v0 = acc0 / z + bb.x;
    float v1 = acc1 / z + bb.y;
    float v2 = acc2 / z + bb.z;
    float v3 = acc3 / z + bb.w;
    v0 = v0 > 0.f ? v0 : expm1f(v0);
    v1 = v1 > 0.f ? v1 : expm1f(v1);
    v2 = v2 > 0.f ? v2 : expm1f(v2);
    v3 = v3 > 0.f ? v3 : expm1f(v3);
    float4 w2a = *(const float4*)&W2[c0 * 2];      // rows c0,c0+1
    float4 w2b = *(const float4*)&W2[c0 * 2 + 4];  // rows c0+2,c0+3
    float s0 = v0 * w2a.x + v1 * w2a.z + v2 * w2b.x + v3 * w2b.z;
    float s1 = v0 * w2a.y + v1 * w2a.w + v2 * w2b.y + v3 * w2b.w;
#pragma unroll
    for (int off = 32; off; off >>= 1) {
        s0 += __shfl_xor(s0, off);
        s1 += __shfl_xor(s1, off);
    }
    if (lane == 0) {
        float4 nd;
        nd.x = s0; nd.y = s1;
        nd.z = s0 * att_src2[0] + s1 * att_src2[1];
        nd.w = s0 * att_dst2[0] + s1 * att_dst2[1];
        nd4[n] = nd;
    }
}

// ---------------------------------------------------------------------------
// K4: layer-2 aggregation, 16 lanes per dst; one 16B gather per edge; d_out.
// ---------------------------------------------------------------------------
__global__ __launch_bounds__(256) void k_agg2(const int* __restrict__ cnt,
                                              const int* __restrict__ csr_src,
                                              const float4* __restrict__ nd4,
                                              const float* __restrict__ b2,
                                              float* __restrict__ out)
{
    const int l = threadIdx.x & 15;
    const int n = blockIdx.x * 16 + (threadIdx.x >> 4);
    if (n >= NN) return;
    int m = cnt[n]; if (m > BCAP) m = BCAP;
    const int base = n << 6;
    const float ad = nd4[n].w;
    float z = 0.f, a0 = 0.f, a1 = 0.f;
    for (int j = l; j < m; j += 16) {
        int s = csr_src[base + j];
        float4 f = nd4[s];
        float ex = __expf(leaky(f.z + ad));
        z  += ex;
        a0 += f.x * ex;
        a1 += f.y * ex;
    }
#pragma unroll
    for (int off = 8; off; off >>= 1) {
        z  += __shfl_xor(z, off);
        a0 += __shfl_xor(a0, off);
        a1 += __shfl_xor(a1, off);
    }
    if (l == 0) {
        out[n * 2 + 0] = a0 / z + b2[0];
        out[n * 2 + 1] = a1 / z + b2[1];
    }
}

extern "C" void kernel_launch(void* const* d_in, const int* in_sizes, int n_in,
                              void* d_out, int out_size, void* d_ws, size_t ws_size,
                              hipStream_t stream)
{
    const float* x        = (const float*)d_in[0];
    const int*   ei       = (const int*)d_in[1];
    const float* W1       = (const float*)d_in[2];
    const float* att_src1 = (const float*)d_in[3];
    const float* att_dst1 = (const float*)d_in[4];
    const float* b1       = (const float*)d_in[5];
    const float* W2       = (const float*)d_in[6];
    const float* att_src2 = (const float*)d_in[7];
    const float* att_dst2 = (const float*)d_in[8];
    const float* b2       = (const float*)d_in[9];
    float* out = (float*)d_out;

    // --- workspace layout (all regions 16B aligned) ---
    int*    csr_src = (int*)d_ws;                            // 12.8 MB
    unsigned short* h1b = (unsigned short*)(csr_src + (size_t)NN * BCAP); // 25.6 MB
    unsigned short* Wt_bf = h1b + (size_t)NN * FH;           // 64 KB
    int*    cnt   = (int*)(Wt_bf + FH * FIN);                // 200 KB
    float*  a_s1  = (float*)(cnt + NN);                      // 800 KB
    float*  a_d1  = a_s1 + (size_t)NN * 4;                   // 800 KB
    float4* nd4   = (float4*)(a_d1 + (size_t)NN * 4);        // 800 KB

    k_prep<<<200, 256, 0, stream>>>(W1, Wt_bf, cnt);
    k_gemm1<<<(NN + 63) / 64, 256, 0, stream>>>(x, Wt_bf, att_src1, att_dst1, h1b, a_s1, a_d1);
    k_scatter<<<(ETOT + 255) / 256, 256, 0, stream>>>(ei, cnt, csr_src);
    k_agg1<<<(NN + 3) / 4, 256, 0, stream>>>(cnt, csr_src, a_s1, a_d1, h1b,
                                             b1, W2, att_src2, att_dst2, nd4);
    k_agg2<<<(NN + 15) / 16, 256, 0, stream>>>(cnt, csr_src, nd4, b2, out);
}

// Round 7
// 233.314 us; speedup vs baseline: 4.9880x; 1.0422x over previous
//
#include <hip/hip_runtime.h>

#define NN     50000
#define E_RAW  800000
#define ETOT   (E_RAW + NN)   /* 850000: edges + self loops */
#define FIN    128
#define FH     256            /* HEADS*HID */
#define NEG    0.2f
#define BCAP   64             /* bucket capacity; P(deg>64) ~ 1e-18 for Poisson(16) */
#define GEMM_NB ((NN + 63) / 64)          /* 782 */
#define SC_NB   ((ETOT + 255) / 256)      /* 3321 */

typedef __attribute__((ext_vector_type(8))) short s16x8;
typedef __attribute__((ext_vector_type(4))) float f32x4;

static __device__ __forceinline__ float leaky(float v) { return v > 0.f ? v : NEG * v; }

// RNE float->bf16
static __device__ __forceinline__ unsigned short f2bf(float f) {
    unsigned u = __float_as_uint(f);
    unsigned r = u + 0x7fffu + ((u >> 16) & 1u);
    return (unsigned short)(r >> 16);
}

// ---------------------------------------------------------------------------
// K0: prep — (a) W1 fp32 [k][col] -> bf16 transposed Wt_bf[col][k];
// (b) zero cnt (replaces memset dispatch).
// ---------------------------------------------------------------------------
__global__ __launch_bounds__(256) void k_prep(const float* __restrict__ W1,
                                              unsigned short* __restrict__ Wt_bf,
                                              int* __restrict__ cnt)
{
    const int b = blockIdx.x, t = threadIdx.x;
    if (b < FIN) Wt_bf[t * FIN + b] = f2bf(W1[b * FH + t]);
    int idx = b * 256 + t;
    if (idx < NN) cnt[idx] = 0;
}

// ---------------------------------------------------------------------------
// K1: FUSED gemm + scatter.  blocks [0,GEMM_NB): h1 = x@W1 via MFMA bf16;
// blocks [GEMM_NB, GEMM_NB+SC_NB): edge bucket-scatter (atomic latency hides
// under MFMA work on co-resident CUs).
// gemm: 64 nodes x 256 cols, 4 waves, wave w = head w.  B-frags read per
// K-iter from L2-hot Wt_bf (no W in LDS); LDS = one 32KB buffer, Xt[64][136]
// during K-loop, reused as Ot[64][256] for the coalesced bf16 store.
// A frag: A[m=lane&15][k=quad*8+j]; C/D: col=lane&15, row=quad*4+reg.
// ---------------------------------------------------------------------------
__global__ __launch_bounds__(256) void k_gx(const float* __restrict__ x,
                                            const unsigned short* __restrict__ Wt_bf,
                                            const float* __restrict__ att_src,
                                            const float* __restrict__ att_dst,
                                            const int* __restrict__ ei,
                                            int* __restrict__ cnt,
                                            int* __restrict__ csr_src,
                                            unsigned short* __restrict__ h1b,
                                            float* __restrict__ a_s,
                                            float* __restrict__ a_d)
{
    const int t = threadIdx.x;

    // ---------------- scatter path ----------------
    if (blockIdx.x >= GEMM_NB) {
        const int e = (blockIdx.x - GEMM_NB) * 256 + t;
        if (e >= ETOT) return;
        int s, d;
        if (e < E_RAW) { s = ei[e]; d = ei[E_RAW + e]; } else { s = e - E_RAW; d = s; }
        int pos = atomicAdd(&cnt[d], 1);
        if (pos >= BCAP) return;   // statistically unreachable
        csr_src[(d << 6) + pos] = s;
        return;
    }

    // ---------------- gemm path ----------------
    __shared__ unsigned short Sbuf[64 * 256];   // 32 KB: Xt (stride 136) then Ot (stride 256)
    const int w    = t >> 6;         // wave id == head
    const int lane = t & 63;
    const int li   = lane & 15;
    const int q8   = (lane >> 4) * 8;
    const int quad = lane >> 4;
    const int n0   = blockIdx.x * 64;

    // --- stage x (fp32 -> bf16 Xt[node][k], stride 136) ---
    {
        const int node_l = t >> 2;
        const int k0 = (t & 3) * 32;
        int nn = n0 + node_l; if (nn >= NN) nn = NN - 1;
        const float* xp = &x[(size_t)nn * FIN + k0];
        unsigned short* xd = &Sbuf[node_l * 136 + k0];
#pragma unroll
        for (int i = 0; i < 8; i++) {
            float4 v = *(const float4*)&xp[i * 4];
            xd[i * 4 + 0] = f2bf(v.x);
            xd[i * 4 + 1] = f2bf(v.y);
            xd[i * 4 + 2] = f2bf(v.z);
            xd[i * 4 + 3] = f2bf(v.w);
        }
    }
    __syncthreads();

    // --- MFMA K-loop; B-frags straight from global (L2-hot) ---
    f32x4 acc[4][4];
#pragma unroll
    for (int i = 0; i < 4; i++)
#pragma unroll
        for (int j = 0; j < 4; j++) acc[i][j] = (f32x4){0.f, 0.f, 0.f, 0.f};

#pragma unroll
    for (int kki = 0; kki < 4; kki++) {
        const int kk = kki * 32;
        s16x8 af[4], bf[4];
#pragma unroll
        for (int n16 = 0; n16 < 4; n16++) {
            int col = w * 64 + n16 * 16 + li;
            bf[n16] = *(const s16x8*)&Wt_bf[col * FIN + kk + q8];
        }
#pragma unroll
        for (int m16 = 0; m16 < 4; m16++)
            af[m16] = *(const s16x8*)&Sbuf[(m16 * 16 + li) * 136 + kk + q8];
#pragma unroll
        for (int m16 = 0; m16 < 4; m16++)
#pragma unroll
            for (int n16 = 0; n16 < 4; n16++)
                acc[m16][n16] = __builtin_amdgcn_mfma_f32_16x16x32_bf16(
                    af[m16], bf[n16], acc[m16][n16], 0, 0, 0);
    }

    // --- epilogue A: per-head attention logits from fp32 acc ---
    {
        float as_c[4], ad_c[4];
#pragma unroll
        for (int n16 = 0; n16 < 4; n16++) {
            int col = w * 64 + n16 * 16 + li;
            as_c[n16] = att_src[col];
            ad_c[n16] = att_dst[col];
        }
#pragma unroll
        for (int m16 = 0; m16 < 4; m16++) {
            float ps[4], pd[4];
#pragma unroll
            for (int reg = 0; reg < 4; reg++) {
                float s = 0.f, d = 0.f;
#pragma unroll
                for (int n16 = 0; n16 < 4; n16++) {
                    s += acc[m16][n16][reg] * as_c[n16];
                    d += acc[m16][n16][reg] * ad_c[n16];
                }
                ps[reg] = s; pd[reg] = d;
            }
#pragma unroll
            for (int off = 1; off < 16; off <<= 1) {
#pragma unroll
                for (int reg = 0; reg < 4; reg++) {
                    ps[reg] += __shfl_xor(ps[reg], off);
                    pd[reg] += __shfl_xor(pd[reg], off);
                }
            }
            if (li == 0) {
#pragma unroll
                for (int reg = 0; reg < 4; reg++) {
                    int node = n0 + m16 * 16 + quad * 4 + reg;
                    if (node < NN) {
                        a_s[node * 4 + w] = ps[reg];
                        a_d[node * 4 + w] = pd[reg];
                    }
                }
            }
        }
    }

    // --- epilogue B: bf16 store via LDS round-trip (Ot reuses Sbuf) ---
    __syncthreads();               // Xt dead
#pragma unroll
    for (int m16 = 0; m16 < 4; m16++)
#pragma unroll
        for (int n16 = 0; n16 < 4; n16++)
#pragma unroll
            for (int reg = 0; reg < 4; reg++)
                Sbuf[(m16 * 16 + quad * 4 + reg) * FH + w * 64 + n16 * 16 + li] =
                    f2bf(acc[m16][n16][reg]);
    __syncthreads();
    {
        const int node_l = t >> 2;
        const int c0 = (t & 3) * 64;
        int node = n0 + node_l;
        if (node < NN) {
#pragma unroll
            for (int i = 0; i < 8; i++)
                *(uint4*)&h1b[(size_t)node * FH + c0 + i * 8] =
                    *(const uint4*)&Sbuf[node_l * FH + c0 + i * 8];
        }
    }
}

// ---------------------------------------------------------------------------
// K2: layer-1 aggregation.  ONE wave per dst; lane l owns channels 4l..4l+3
// (head = l>>4).  Per edge: 1x 8B gather + per-lane a_s1 load + in-loop exp.
// FUSED: /z, +b1, ELU (via __expf), W2 projection, layer-2 logits -> nd4.
// ---------------------------------------------------------------------------
__global__ __launch_bounds__(256) void k_agg1(const int* __restrict__ cnt,
                                              const int* __restrict__ csr_src,
                                              const float* __restrict__ a_s1,
                                              const float* __restrict__ a_d1,
                                              const unsigned short* __restrict__ h1b,
                                              const float* __restrict__ b1,
                                              const float* __restrict__ W2,
                                              const float* __restrict__ att_src2,
                                              const float* __restrict__ att_dst2,
                                              float4* __restrict__ nd4)
{
    const int lane = threadIdx.x & 63;
    const int n = blockIdx.x * 4 + (threadIdx.x >> 6);
    if (n >= NN) return;
    int m = cnt[n]; if (m > BCAP) m = BCAP;
    const int base = n << 6;
    const int h = lane >> 4;                     // head of this lane
    const float ad_h = a_d1[n * 4 + h];
    float acc0 = 0.f, acc1 = 0.f, acc2 = 0.f, acc3 = 0.f, z = 0.f;
    const int* sp = &csr_src[base];
#pragma unroll 4
    for (int j = 0; j < m; j++) {
        int s = sp[j];                           // wave-uniform 4B
        float as_h = a_s1[s * 4 + h];            // 4 addrs/wave, L2-hot
        float ex = __expf(leaky(as_h + ad_h));
        unsigned long long wv =
            *(const unsigned long long*)(h1b + (size_t)s * FH + lane * 4);
        unsigned lo = (unsigned)wv, hi = (unsigned)(wv >> 32);
        acc0 += __uint_as_float(lo << 16) * ex;
        acc1 += __uint_as_float(lo & 0xffff0000u) * ex;
        acc2 += __uint_as_float(hi << 16) * ex;
        acc3 += __uint_as_float(hi & 0xffff0000u) * ex;
        z += ex;
    }
    const int c0 = lane * 4;
    float4 bb = *(const float4*)&b1[c0];
    float v0 = acc0 / z + bb.x;
    float v1 = acc1 / z + bb.y;
    float v2 = acc2 / z + bb.z;
    float v3 = acc3 / z + bb.w;
    v0 = v0 > 0.f ? v0 : __expf(v0) - 1.f;   // ELU; |err| < 1e-7 rel, fine
    v1 = v1 > 0.f ? v1 : __expf(v1) - 1.f;
    v2 = v2 > 0.f ? v2 : __expf(v2) - 1.f;
    v3 = v3 > 0.f ? v3 : __expf(v3) - 1.f;
    float4 w2a = *(const float4*)&W2[c0 * 2];      // rows c0,c0+1
    float4 w2b = *(const float4*)&W2[c0 * 2 + 4];  // rows c0+2,c0+3
    float s0 = v0 * w2a.x + v1 * w2a.z + v2 * w2b.x + v3 * w2b.z;
    float s1 = v0 * w2a.y + v1 * w2a.w + v2 * w2b.y + v3 * w2b.w;
#pragma unroll
    for (int off = 32; off; off >>= 1) {
        s0 += __shfl_xor(s0, off);
        s1 += __shfl_xor(s1, off);
    }
    if (lane == 0) {
        float4 nd;
        nd.x = s0; nd.y = s1;
        nd.z = s0 * att_src2[0] + s1 * att_src2[1];
        nd.w = s0 * att_dst2[0] + s1 * att_dst2[1];
        nd4[n] = nd;
    }
}

// ---------------------------------------------------------------------------
// K3: layer-2 aggregation, 16 lanes per dst; one 16B gather per edge; d_out.
// ---------------------------------------------------------------------------
__global__ __launch_bounds__(256) void k_agg2(const int* __restrict__ cnt,
                                              const int* __restrict__ csr_src,
                                              const float4* __restrict__ nd4,
                                              const float* __restrict__ b2,
                                              float* __restrict__ out)
{
    const int l = threadIdx.x & 15;
    const int n = blockIdx.x * 16 + (threadIdx.x >> 4);
    if (n >= NN) return;
    int m = cnt[n]; if (m > BCAP) m = BCAP;
    const int base = n << 6;
    const float ad = nd4[n].w;
    float z = 0.f, a0 = 0.f, a1 = 0.f;
    for (int j = l; j < m; j += 16) {
        int s = csr_src[base + j];
        float4 f = nd4[s];
        float ex = __expf(leaky(f.z + ad));
        z  += ex;
        a0 += f.x * ex;
        a1 += f.y * ex;
    }
#pragma unroll
    for (int off = 8; off; off >>= 1) {
        z  += __shfl_xor(z, off);
        a0 += __shfl_xor(a0, off);
        a1 += __shfl_xor(a1, off);
    }
    if (l == 0) {
        out[n * 2 + 0] = a0 / z + b2[0];
        out[n * 2 + 1] = a1 / z + b2[1];
    }
}

extern "C" void kernel_launch(void* const* d_in, const int* in_sizes, int n_in,
                              void* d_out, int out_size, void* d_ws, size_t ws_size,
                              hipStream_t stream)
{
    const float* x        = (const float*)d_in[0];
    const int*   ei       = (const int*)d_in[1];
    const float* W1       = (const float*)d_in[2];
    const float* att_src1 = (const float*)d_in[3];
    const float* att_dst1 = (const float*)d_in[4];
    const float* b1       = (const float*)d_in[5];
    const float* W2       = (const float*)d_in[6];
    const float* att_src2 = (const float*)d_in[7];
    const float* att_dst2 = (const float*)d_in[8];
    const float* b2       = (const float*)d_in[9];
    float* out = (float*)d_out;

    // --- workspace layout (all regions 16B aligned) ---
    int*    csr_src = (int*)d_ws;                            // 12.8 MB
    unsigned short* h1b = (unsigned short*)(csr_src + (size_t)NN * BCAP); // 25.6 MB
    unsigned short* Wt_bf = h1b + (size_t)NN * FH;           // 64 KB
    int*    cnt   = (int*)(Wt_bf + FH * FIN);                // 200 KB
    float*  a_s1  = (float*)(cnt + NN);                      // 800 KB
    float*  a_d1  = a_s1 + (size_t)NN * 4;                   // 800 KB
    float4* nd4   = (float4*)(a_d1 + (size_t)NN * 4);        // 800 KB

    k_prep<<<200, 256, 0, stream>>>(W1, Wt_bf, cnt);
    k_gx<<<GEMM_NB + SC_NB, 256, 0, stream>>>(x, Wt_bf, att_src1, att_dst1, ei,
                                              cnt, csr_src, h1b, a_s1, a_d1);
    k_agg1<<<(NN + 3) / 4, 256, 0, stream>>>(cnt, csr_src, a_s1, a_d1, h1b,
                                             b1, W2, att_src2, att_dst2, nd4);
    k_agg2<<<(NN + 15) / 16, 256, 0, stream>>>(cnt, csr_src, nd4, b2, out);
}

// Round 8
// 225.785 us; speedup vs baseline: 5.1544x; 1.0333x over previous
//
#include <hip/hip_runtime.h>

#define NN     50000
#define E_RAW  800000
#define ETOT   (E_RAW + NN)   /* 850000: edges + self loops */
#define FIN    128
#define FH     256            /* HEADS*HID */
#define NEG    0.2f
#define BCAP   64             /* bucket capacity; P(deg>64) ~ 1e-18 for Poisson(16) */
#define EPT    4                            /* scatter edges per thread (ILP) */
#define SC_TH  ((ETOT + EPT - 1) / EPT)     /* 212500 scatter threads */
#define SC_NB  ((SC_TH + 255) / 256)        /* 831 scatter blocks */
#define SC_STR (SC_NB * 256)                /* 212736 grid stride */
#define GEMM_NB ((NN + 63) / 64)            /* 782 gemm blocks */

typedef __attribute__((ext_vector_type(8))) short s16x8;
typedef __attribute__((ext_vector_type(4))) float f32x4;

static __device__ __forceinline__ float leaky(float v) { return v > 0.f ? v : NEG * v; }

// RNE float->bf16
static __device__ __forceinline__ unsigned short f2bf(float f) {
    unsigned u = __float_as_uint(f);
    unsigned r = u + 0x7fffu + ((u >> 16) & 1u);
    return (unsigned short)(r >> 16);
}

// ---------------------------------------------------------------------------
// K0: prep — (a) W1 fp32 [k][col] -> bf16 transposed Wt_bf[col][k];
// (b) zero cnt (replaces memset dispatch).
// ---------------------------------------------------------------------------
__global__ __launch_bounds__(256) void k_prep(const float* __restrict__ W1,
                                              unsigned short* __restrict__ Wt_bf,
                                              int* __restrict__ cnt)
{
    const int b = blockIdx.x, t = threadIdx.x;
    if (b < FIN) Wt_bf[t * FIN + b] = f2bf(W1[b * FH + t]);
    int idx = b * 256 + t;
    if (idx < NN) cnt[idx] = 0;
}

// ---------------------------------------------------------------------------
// K1: FUSED scatter + gemm.  blocks [0, SC_NB): edge bucket-scatter with
// EPT=4 independent atomic chains per thread (ILP over the ~900cyc returning
// atomic); scatter first so the long pole starts at t=0.
// blocks [SC_NB, SC_NB+GEMM_NB): h1 = x@W1 via MFMA bf16 (unchanged R7 path).
// ---------------------------------------------------------------------------
__global__ __launch_bounds__(256) void k_gx(const float* __restrict__ x,
                                            const unsigned short* __restrict__ Wt_bf,
                                            const float* __restrict__ att_src,
                                            const float* __restrict__ att_dst,
                                            const int* __restrict__ ei,
                                            int* __restrict__ cnt,
                                            int* __restrict__ csr_src,
                                            unsigned short* __restrict__ h1b,
                                            float* __restrict__ a_s,
                                            float* __restrict__ a_d)
{
    const int t = threadIdx.x;

    // ---------------- scatter path (first) ----------------
    if (blockIdx.x < SC_NB) {
        const int tid = blockIdx.x * 256 + t;
        int sv[EPT], dv[EPT], pv[EPT];
        bool val[EPT];
#pragma unroll
        for (int k = 0; k < EPT; k++) {
            int e = tid + k * SC_STR;
            val[k] = (e < ETOT);
            sv[k] = 0; dv[k] = 0;
            if (val[k]) {
                if (e < E_RAW) { sv[k] = ei[e]; dv[k] = ei[E_RAW + e]; }
                else           { sv[k] = e - E_RAW; dv[k] = sv[k]; }
            }
        }
#pragma unroll
        for (int k = 0; k < EPT; k++)
            if (val[k]) pv[k] = atomicAdd(&cnt[dv[k]], 1);
#pragma unroll
        for (int k = 0; k < EPT; k++)
            if (val[k] && pv[k] < BCAP)
                csr_src[(dv[k] << 6) + pv[k]] = sv[k];
        return;
    }

    // ---------------- gemm path ----------------
    __shared__ unsigned short Sbuf[64 * 256];   // 32 KB: Xt (stride 136) then Ot (stride 256)
    const int w    = t >> 6;         // wave id == head
    const int lane = t & 63;
    const int li   = lane & 15;
    const int q8   = (lane >> 4) * 8;
    const int quad = lane >> 4;
    const int n0   = (blockIdx.x - SC_NB) * 64;

    // --- stage x (fp32 -> bf16 Xt[node][k], stride 136) ---
    {
        const int node_l = t >> 2;
        const int k0 = (t & 3) * 32;
        int nn = n0 + node_l; if (nn >= NN) nn = NN - 1;
        const float* xp = &x[(size_t)nn * FIN + k0];
        unsigned short* xd = &Sbuf[node_l * 136 + k0];
#pragma unroll
        for (int i = 0; i < 8; i++) {
            float4 v = *(const float4*)&xp[i * 4];
            xd[i * 4 + 0] = f2bf(v.x);
            xd[i * 4 + 1] = f2bf(v.y);
            xd[i * 4 + 2] = f2bf(v.z);
            xd[i * 4 + 3] = f2bf(v.w);
        }
    }
    __syncthreads();

    // --- MFMA K-loop; B-frags straight from global (L2-hot) ---
    f32x4 acc[4][4];
#pragma unroll
    for (int i = 0; i < 4; i++)
#pragma unroll
        for (int j = 0; j < 4; j++) acc[i][j] = (f32x4){0.f, 0.f, 0.f, 0.f};

#pragma unroll
    for (int kki = 0; kki < 4; kki++) {
        const int kk = kki * 32;
        s16x8 af[4], bf[4];
#pragma unroll
        for (int n16 = 0; n16 < 4; n16++) {
            int col = w * 64 + n16 * 16 + li;
            bf[n16] = *(const s16x8*)&Wt_bf[col * FIN + kk + q8];
        }
#pragma unroll
        for (int m16 = 0; m16 < 4; m16++)
            af[m16] = *(const s16x8*)&Sbuf[(m16 * 16 + li) * 136 + kk + q8];
#pragma unroll
        for (int m16 = 0; m16 < 4; m16++)
#pragma unroll
            for (int n16 = 0; n16 < 4; n16++)
                acc[m16][n16] = __builtin_amdgcn_mfma_f32_16x16x32_bf16(
                    af[m16], bf[n16], acc[m16][n16], 0, 0, 0);
    }

    // --- epilogue A: per-head attention logits from fp32 acc ---
    {
        float as_c[4], ad_c[4];
#pragma unroll
        for (int n16 = 0; n16 < 4; n16++) {
            int col = w * 64 + n16 * 16 + li;
            as_c[n16] = att_src[col];
            ad_c[n16] = att_dst[col];
        }
#pragma unroll
        for (int m16 = 0; m16 < 4; m16++) {
            float ps[4], pd[4];
#pragma unroll
            for (int reg = 0; reg < 4; reg++) {
                float s = 0.f, d = 0.f;
#pragma unroll
                for (int n16 = 0; n16 < 4; n16++) {
                    s += acc[m16][n16][reg] * as_c[n16];
                    d += acc[m16][n16][reg] * ad_c[n16];
                }
                ps[reg] = s; pd[reg] = d;
            }
#pragma unroll
            for (int off = 1; off < 16; off <<= 1) {
#pragma unroll
                for (int reg = 0; reg < 4; reg++) {
                    ps[reg] += __shfl_xor(ps[reg], off);
                    pd[reg] += __shfl_xor(pd[reg], off);
                }
            }
            if (li == 0) {
#pragma unroll
                for (int reg = 0; reg < 4; reg++) {
                    int node = n0 + m16 * 16 + quad * 4 + reg;
                    if (node < NN) {
                        a_s[node * 4 + w] = ps[reg];
                        a_d[node * 4 + w] = pd[reg];
                    }
                }
            }
        }
    }

    // --- epilogue B: bf16 store via LDS round-trip (Ot reuses Sbuf) ---
    __syncthreads();               // Xt dead
#pragma unroll
    for (int m16 = 0; m16 < 4; m16++)
#pragma unroll
        for (int n16 = 0; n16 < 4; n16++)
#pragma unroll
            for (int reg = 0; reg < 4; reg++)
                Sbuf[(m16 * 16 + quad * 4 + reg) * FH + w * 64 + n16 * 16 + li] =
                    f2bf(acc[m16][n16][reg]);
    __syncthreads();
    {
        const int node_l = t >> 2;
        const int c0 = (t & 3) * 64;
        int node = n0 + node_l;
        if (node < NN) {
#pragma unroll
            for (int i = 0; i < 8; i++)
                *(uint4*)&h1b[(size_t)node * FH + c0 + i * 8] =
                    *(const uint4*)&Sbuf[node_l * FH + c0 + i * 8];
        }
    }
}

// ---------------------------------------------------------------------------
// K2: layer-1 aggregation.  ONE wave per dst; lane l owns channels 4l..4l+3
// (head = l>>4).  Per edge: 1x 8B gather + per-lane a_s1 load + in-loop exp.
// FUSED: /z, +b1, ELU (via __expf), W2 projection, layer-2 logits -> nd4.
// ---------------------------------------------------------------------------
__global__ __launch_bounds__(256) void k_agg1(const int* __restrict__ cnt,
                                              const int* __restrict__ csr_src,
                                              const float* __restrict__ a_s1,
                                              const float* __restrict__ a_d1,
                                              const unsigned short* __restrict__ h1b,
                                              const float* __restrict__ b1,
                                              const float* __restrict__ W2,
                                              const float* __restrict__ att_src2,
                                              const float* __restrict__ att_dst2,
                                              float4* __restrict__ nd4)
{
    const int lane = threadIdx.x & 63;
    const int n = blockIdx.x * 4 + (threadIdx.x >> 6);
    if (n >= NN) return;
    int m = cnt[n]; if (m > BCAP) m = BCAP;
    const int base = n << 6;
    const int h = lane >> 4;                     // head of this lane
    const float ad_h = a_d1[n * 4 + h];
    float acc0 = 0.f, acc1 = 0.f, acc2 = 0.f, acc3 = 0.f, z = 0.f;
    const int* sp = &csr_src[base];
#pragma unroll 4
    for (int j = 0; j < m; j++) {
        int s = sp[j];                           // wave-uniform 4B
        float as_h = a_s1[s * 4 + h];            // 4 addrs/wave, L2-hot
        float ex = __expf(leaky(as_h + ad_h));
        unsigned long long wv =
            *(const unsigned long long*)(h1b + (size_t)s * FH + lane * 4);
        unsigned lo = (unsigned)wv, hi = (unsigned)(wv >> 32);
        acc0 += __uint_as_float(lo << 16) * ex;
        acc1 += __uint_as_float(lo & 0xffff0000u) * ex;
        acc2 += __uint_as_float(hi << 16) * ex;
        acc3 += __uint_as_float(hi & 0xffff0000u) * ex;
        z += ex;
    }
    const int c0 = lane * 4;
    float4 bb = *(const float4*)&b1[c0];
    float v0 = acc0 / z + bb.x;
    float v1 = acc1 / z + bb.y;
    float v2 = acc2 / z + bb.z;
    float v3 = acc3 / z + bb.w;
    v0 = v0 > 0.f ? v0 : __expf(v0) - 1.f;   // ELU
    v1 = v1 > 0.f ? v1 : __expf(v1) - 1.f;
    v2 = v2 > 0.f ? v2 : __expf(v2) - 1.f;
    v3 = v3 > 0.f ? v3 : __expf(v3) - 1.f;
    float4 w2a = *(const float4*)&W2[c0 * 2];      // rows c0,c0+1
    float4 w2b = *(const float4*)&W2[c0 * 2 + 4];  // rows c0+2,c0+3
    float s0 = v0 * w2a.x + v1 * w2a.z + v2 * w2b.x + v3 * w2b.z;
    float s1 = v0 * w2a.y + v1 * w2a.w + v2 * w2b.y + v3 * w2b.w;
#pragma unroll
    for (int off = 32; off; off >>= 1) {
        s0 += __shfl_xor(s0, off);
        s1 += __shfl_xor(s1, off);
    }
    if (lane == 0) {
        float4 nd;
        nd.x = s0; nd.y = s1;
        nd.z = s0 * att_src2[0] + s1 * att_src2[1];
        nd.w = s0 * att_dst2[0] + s1 * att_dst2[1];
        nd4[n] = nd;
    }
}

// ---------------------------------------------------------------------------
// K3: layer-2 aggregation, 16 lanes per dst; one 16B gather per edge; d_out.
// ---------------------------------------------------------------------------
__global__ __launch_bounds__(256) void k_agg2(const int* __restrict__ cnt,
                                              const int* __restrict__ csr_src,
                                              const float4* __restrict__ nd4,
                                              const float* __restrict__ b2,
                                              float* __restrict__ out)
{
    const int l = threadIdx.x & 15;
    const int n = blockIdx.x * 16 + (threadIdx.x >> 4);
    if (n >= NN) return;
    int m = cnt[n]; if (m > BCAP) m = BCAP;
    const int base = n << 6;
    const float ad = nd4[n].w;
    float z = 0.f, a0 = 0.f, a1 = 0.f;
    for (int j = l; j < m; j += 16) {
        int s = csr_src[base + j];
        float4 f = nd4[s];
        float ex = __expf(leaky(f.z + ad));
        z  += ex;
        a0 += f.x * ex;
        a1 += f.y * ex;
    }
#pragma unroll
    for (int off = 8; off; off >>= 1) {
        z  += __shfl_xor(z, off);
        a0 += __shfl_xor(a0, off);
        a1 += __shfl_xor(a1, off);
    }
    if (l == 0) {
        out[n * 2 + 0] = a0 / z + b2[0];
        out[n * 2 + 1] = a1 / z + b2[1];
    }
}

extern "C" void kernel_launch(void* const* d_in, const int* in_sizes, int n_in,
                              void* d_out, int out_size, void* d_ws, size_t ws_size,
                              hipStream_t stream)
{
    const float* x        = (const float*)d_in[0];
    const int*   ei       = (const int*)d_in[1];
    const float* W1       = (const float*)d_in[2];
    const float* att_src1 = (const float*)d_in[3];
    const float* att_dst1 = (const float*)d_in[4];
    const float* b1       = (const float*)d_in[5];
    const float* W2       = (const float*)d_in[6];
    const float* att_src2 = (const float*)d_in[7];
    const float* att_dst2 = (const float*)d_in[8];
    const float* b2       = (const float*)d_in[9];
    float* out = (float*)d_out;

    // --- workspace layout (all regions 16B aligned) ---
    int*    csr_src = (int*)d_ws;                            // 12.8 MB
    unsigned short* h1b = (unsigned short*)(csr_src + (size_t)NN * BCAP); // 25.6 MB
    unsigned short* Wt_bf = h1b + (size_t)NN * FH;           // 64 KB
    int*    cnt   = (int*)(Wt_bf + FH * FIN);                // 200 KB
    float*  a_s1  = (float*)(cnt + NN);                      // 800 KB
    float*  a_d1  = a_s1 + (size_t)NN * 4;                   // 800 KB
    float4* nd4   = (float4*)(a_d1 + (size_t)NN * 4);        // 800 KB

    k_prep<<<200, 256, 0, stream>>>(W1, Wt_bf, cnt);
    k_gx<<<SC_NB + GEMM_NB, 256, 0, stream>>>(x, Wt_bf, att_src1, att_dst1, ei,
                                              cnt, csr_src, h1b, a_s1, a_d1);
    k_agg1<<<(NN + 3) / 4, 256, 0, stream>>>(cnt, csr_src, a_s1, a_d1, h1b,
                                             b1, W2, att_src2, att_dst2, nd4);
    k_agg2<<<(NN + 15) / 16, 256, 0, stream>>>(cnt, csr_src, nd4, b2, out);
}